// Round 1
// 179.748 us; speedup vs baseline: 1.0840x; 1.0840x over previous
//
#include <hip/hip_runtime.h>
#include <cstddef>

// B=2048, C_IN=C_OUT=64, T=32, E=32768, K_HOPS=2, KSIZE=3
#define NB   2048
#define NE   32768
#define NTC  2048      // T*C elems per node
#define SLOPE_F 0.01f
#define EPS_F   1e-5f

typedef short bf16x8 __attribute__((ext_vector_type(8)));
typedef float f32x4  __attribute__((ext_vector_type(4)));

// bf16 helpers (manual, RNE pack)
__device__ __forceinline__ unsigned short f2bf(float f) {
    unsigned u = __builtin_bit_cast(unsigned, f);
    u += 0x7FFF + ((u >> 16) & 1);
    return (unsigned short)(u >> 16);
}
__device__ __forceinline__ float bflo(unsigned v) {
    return __builtin_bit_cast(float, v << 16);
}
__device__ __forceinline__ float bfhi(unsigned v) {
    return __builtin_bit_cast(float, v & 0xFFFF0000u);
}
__device__ __forceinline__ unsigned pk2(float lo, float hi) {
    return (unsigned)f2bf(lo) | ((unsigned)f2bf(hi) << 16);
}
// unpack-accumulate 8 bf16 lanes of a uint4 into acc[0..7]
__device__ __forceinline__ void accv8(float* acc, const uint4& v, float wt) {
    acc[0] += wt * bflo(v.x); acc[1] += wt * bfhi(v.x);
    acc[2] += wt * bflo(v.y); acc[3] += wt * bfhi(v.y);
    acc[4] += wt * bflo(v.z); acc[5] += wt * bfhi(v.z);
    acc[6] += wt * bflo(v.w); acc[7] += wt * bfhi(v.w);
}
// unpack-accumulate 8 int16 lanes of a uint4 into acc[0..7] (wt has scale folded)
__device__ __forceinline__ void acci16(float* acc, const uint4& v, float wt) {
    acc[0] += wt * (float)(short)(v.x & 0xFFFFu); acc[1] += wt * (float)(short)(v.x >> 16);
    acc[2] += wt * (float)(short)(v.y & 0xFFFFu); acc[3] += wt * (float)(short)(v.y >> 16);
    acc[4] += wt * (float)(short)(v.z & 0xFFFFu); acc[5] += wt * (float)(short)(v.z >> 16);
    acc[6] += wt * (float)(short)(v.w & 0xFFFFu); acc[7] += wt * (float)(short)(v.w >> 16);
}
__device__ __forceinline__ unsigned pkq2(float a, float b, float inv) {
    int qa = __float2int_rn(a * inv);
    int qb = __float2int_rn(b * inv);
    return ((unsigned)qa & 0xFFFFu) | ((unsigned)qb << 16);
}

// ---------------- edge-index width handling ----------------
__global__ __launch_bounds__(256)
void k_detect(const int* __restrict__ ei, int* __restrict__ mode)
{
    int k = blockIdx.x * 256 + threadIdx.x;
    if (ei[2 * k + 1] != 0) atomicOr(mode, 1);  // 1 => int32 layout
}

__device__ __forceinline__ int edge_src(const int* ei, int m, int e) {
    return m ? ei[e] : ei[2 * e];
}
__device__ __forceinline__ int edge_dst(const int* ei, int m, int e) {
    return m ? ei[NE + e] : ei[2 * (NE + e)];
}

// hist + weight packs:
//   blocks 0..47:  wAb[(kk*64+o)*64+i] = bf16 w[o][i][kk]     (conv A-layout)
//   blocks 48..95: twB[m][g*64+k]      = bf16 tw[m][k][g]     (tag B-layout, W^T)
__global__ __launch_bounds__(256)
void k_hist(const int* __restrict__ ei, const int* __restrict__ mode,
            int* __restrict__ hist, const float* __restrict__ cw,
            unsigned short* __restrict__ wAb, const float* __restrict__ tw,
            unsigned short* __restrict__ twB)
{
    int e = blockIdx.x * 256 + threadIdx.x;
    int m = *mode;
    atomicAdd(&hist[edge_dst(ei, m, e)], 1);
    if (blockIdx.x < 48) {
        int idx = e;                      // 0..12287
        int kk = idx >> 12, o = (idx >> 6) & 63, i = idx & 63;
        wAb[idx] = f2bf(cw[o * 192 + i * 3 + kk]);
    } else if (blockIdx.x < 96) {
        int idx = e - 48 * 256;           // 0..12287
        int mm = idx >> 12, rem = idx & 4095;
        int g = rem >> 6, k = rem & 63;
        twB[idx] = f2bf(tw[mm * 4096 + k * 64 + g]);
    }
}

// single block: CSR row-pointer scan
__global__ __launch_bounds__(256)
void k_scan(const int* __restrict__ hist, int* __restrict__ rowp, int* __restrict__ cur)
{
    __shared__ int part[256];
    int j = threadIdx.x;
    int loc[8]; int s = 0;
#pragma unroll
    for (int r = 0; r < 8; ++r) { loc[r] = hist[j * 8 + r]; s += loc[r]; }
    part[j] = s;
    __syncthreads();
    for (int off = 1; off < 256; off <<= 1) {
        int v = (j >= off) ? part[j - off] : 0;
        __syncthreads();
        part[j] += v;
        __syncthreads();
    }
    int excl = part[j] - s;
#pragma unroll
    for (int r = 0; r < 8; ++r) {
        rowp[j * 8 + r] = excl;
        cur [j * 8 + r] = excl;
        excl += loc[r];
    }
    if (j == 255) rowp[2048] = excl;  // == NE
}

__global__ __launch_bounds__(256)
void k_scat(const int* __restrict__ ei, const float* __restrict__ ew,
            const int* __restrict__ mode, int* __restrict__ cur,
            int* __restrict__ csrs, float* __restrict__ csrw)
{
    int e = blockIdx.x * 256 + threadIdx.x;
    int m = *mode;
    int d = edge_dst(ei, m, e);
    int pos = atomicAdd(&cur[d], 1);
    csrs[pos] = edge_src(ei, m, e);
    csrw[pos] = ew[e];
}

// ---------------- conv1d (MFMA) + leaky + LayerNorm + BN partials ----------
// R12 body (fast: no spills, coalesced h-store via LDS bounce, shuffle BN)
__global__ __launch_bounds__(256, 4)
void k_convln(const float* __restrict__ x, const unsigned short* __restrict__ wAb,
              const float* __restrict__ cb, const float* __restrict__ lg,
              const float* __restrict__ lb, float* __restrict__ h_in,
              float* __restrict__ partials)
{
    __shared__ __align__(16) unsigned short xT[36 * 72];
    __shared__ float hT[32 * 65];
    __shared__ float red1[64], red2[64];
    __shared__ float wsum[8];
    __shared__ float bcast[2];

    const int b = blockIdx.x, j = threadIdx.x;
    const float* __restrict__ xg = x + (size_t)b * NTC;

    {   // stage x -> bf16 xT[t+2][i]; zero-pad rows 0,1,34,35
        unsigned* xTd = (unsigned*)xT;
        int t = j & 31, p = j >> 5;
#pragma unroll
        for (int r = 0; r < 4; ++r) {
            int i0 = (r * 8 + p) * 2;
            float v0 = xg[i0 * 32 + t];
            float v1 = xg[(i0 + 1) * 32 + t];
            xTd[(t + 2) * 36 + (i0 >> 1)] = pk2(v0, v1);
        }
        if (j < 72)       xTd[j] = 0u;
        else if (j < 144) xTd[1224 + (j - 72)] = 0u;   // rows 34,35
    }
    __syncthreads();

    const int lane = j & 63, w = j >> 6;
    const int n16 = lane & 15, quad = lane >> 4;

    bf16x8 afr[3][2];
#pragma unroll
    for (int kk = 0; kk < 3; ++kk)
#pragma unroll
        for (int s = 0; s < 2; ++s) {
            int off16 = (kk * 64 + w * 16 + n16) * 64 + s * 32 + quad * 8;
            afr[kk][s] = *(const bf16x8*)(wAb + off16);
        }

    f32x4 acc0 = {0.f, 0.f, 0.f, 0.f};
    f32x4 acc1 = {0.f, 0.f, 0.f, 0.f};
#pragma unroll
    for (int kk = 0; kk < 3; ++kk)
#pragma unroll
        for (int s = 0; s < 2; ++s) {
            bf16x8 b0 = *(const bf16x8*)(xT + (n16 + kk) * 72 + s * 32 + quad * 8);
            bf16x8 b1 = *(const bf16x8*)(xT + (16 + n16 + kk) * 72 + s * 32 + quad * 8);
            acc0 = __builtin_amdgcn_mfma_f32_16x16x32_bf16(afr[kk][s], b0, acc0, 0, 0, 0);
            acc1 = __builtin_amdgcn_mfma_f32_16x16x32_bf16(afr[kk][s], b1, acc1, 0, 0, 0);
        }

    float vals[2][4];
    float s1 = 0.f, s2 = 0.f;
#pragma unroll
    for (int r = 0; r < 4; ++r) {
        float cbv = cb[w * 16 + quad * 4 + r];
        float v0 = acc0[r] + cbv;
        float v1 = acc1[r] + cbv;
        v0 = (v0 >= 0.f) ? v0 : SLOPE_F * v0;
        v1 = (v1 >= 0.f) ? v1 : SLOPE_F * v1;
        vals[0][r] = v0; vals[1][r] = v1;
        s1 += v0 + v1; s2 += v0 * v0 + v1 * v1;
    }
#pragma unroll
    for (int off = 32; off > 0; off >>= 1) {
        s1 += __shfl_down(s1, off, 64);
        s2 += __shfl_down(s2, off, 64);
    }
    if (lane == 0) { wsum[w] = s1; wsum[4 + w] = s2; }
    __syncthreads();
    if (j == 0) {
        float S1 = wsum[0] + wsum[1] + wsum[2] + wsum[3];
        float S2 = wsum[4] + wsum[5] + wsum[6] + wsum[7];
        float mu  = S1 * (1.f / 2048.f);
        float var = S2 * (1.f / 2048.f) - mu * mu;
        bcast[0] = mu;
        bcast[1] = rsqrtf(var + EPS_F);
    }
    __syncthreads();
    const float mu = bcast[0], rs = bcast[1];
    float po1[4] = {0.f, 0.f, 0.f, 0.f}, po2[4] = {0.f, 0.f, 0.f, 0.f};
#pragma unroll
    for (int nt = 0; nt < 2; ++nt) {
        int t = nt * 16 + n16;
#pragma unroll
        for (int r = 0; r < 4; ++r) {
            int o = w * 16 + quad * 4 + r;
            float h = (vals[nt][r] - mu) * rs * lg[o * 32 + t] + lb[o * 32 + t];
            hT[t * 65 + o] = h;
            po1[r] += h; po2[r] += h * h;
        }
    }
#pragma unroll
    for (int off = 8; off > 0; off >>= 1) {
#pragma unroll
        for (int r = 0; r < 4; ++r) {
            po1[r] += __shfl_down(po1[r], off, 16);
            po2[r] += __shfl_down(po2[r], off, 16);
        }
    }
    if (n16 == 0) {
#pragma unroll
        for (int r = 0; r < 4; ++r) {
            int o = w * 16 + quad * 4 + r;
            red1[o] = po1[r];
            red2[o] = po2[r];
        }
    }
    __syncthreads();
    float* hb = h_in + (size_t)b * NTC;
#pragma unroll
    for (int r = 0; r < 8; ++r) {                  // coalesced h_in store
        int idx = j + r * 256;
        hb[idx] = hT[(idx >> 6) * 65 + (idx & 63)];
    }
    float* pb_ = partials + (size_t)b * 128;       // coalesced 512B store
    if (j < 64)       pb_[j] = red1[j];
    else if (j < 128) pb_[j] = red2[j - 64];
}

// ---------------- reduce partials -> BN scale/shift ----------------
__global__ __launch_bounds__(256)
void k_bnred(const float* __restrict__ partials, const float* __restrict__ bg,
             const float* __restrict__ bb, float* __restrict__ stats)
{
    const int c = blockIdx.x, j = threadIdx.x;
    float s1 = 0.f, s2 = 0.f;
    for (int b = j; b < NB; b += 256) {
        const float* p = partials + (size_t)b * 128;
        s1 += p[c];
        s2 += p[64 + c];
    }
    __shared__ float r1[4], r2[4];
#pragma unroll
    for (int off = 32; off > 0; off >>= 1) {
        s1 += __shfl_down(s1, off, 64);
        s2 += __shfl_down(s2, off, 64);
    }
    if ((j & 63) == 0) { r1[j >> 6] = s1; r2[j >> 6] = s2; }
    __syncthreads();
    if (j == 0) {
        float S1 = r1[0] + r1[1] + r1[2] + r1[3];
        float S2 = r2[0] + r2[1] + r2[2] + r2[3];
        const float inv_n = 1.f / 65536.f;
        float mu  = S1 * inv_n;
        float var = S2 * inv_n - mu * mu;
        float rs  = rsqrtf(var + EPS_F);
        float sc  = bg[c] * rs;
        stats[128 + c] = sc;
        stats[192 + c] = bb[c] - mu * sc;
    }
}

// ---------------- z = leaky(BN(h)); out = h + z@W0 + tag_b (MFMA) ----------
// z has magnitude ~1 -> bf16 error here is negligible.
__global__ __launch_bounds__(256, 6)
void k_zw0(const float* __restrict__ h_in, const float* __restrict__ stats,
           const unsigned short* __restrict__ twB, const float* __restrict__ tb,
           unsigned short* __restrict__ zb16, float* __restrict__ out)
{
    __shared__ __align__(16) unsigned short zA[32 * 64];  // bf16 z, 4KB
    __shared__ float hl[32 * 65];                          // fp32 h residual
    const int b = blockIdx.x, j = threadIdx.x;
    const int c = j & 63;
    const float sc = stats[128 + c], sh = stats[192 + c];
    const float* hb = h_in + (size_t)b * NTC;
    unsigned short* zb = zb16 + (size_t)b * NTC;
#pragma unroll
    for (int r = 0; r < 8; ++r) {
        int idx = j + r * 256;                    // idx = t*64 + c
        int t = idx >> 6;
        float h = hb[idx];
        float zv = h * sc + sh;
        zv = (zv >= 0.f) ? zv : SLOPE_F * zv;
        unsigned short zh = f2bf(zv);
        zb[idx] = zh;                             // bf16 payload for hop1
        zA[idx] = zh;                             // same layout t*64+c
        hl[t * 65 + c] = h;
    }
    __syncthreads();
    const int lane = j & 63, w = j >> 6;
    const int n16 = lane & 15, quad = lane >> 4;
    const int g = w * 16 + n16;

    bf16x8 a00 = *(const bf16x8*)(zA + (n16)      * 64 +      quad * 8);
    bf16x8 a01 = *(const bf16x8*)(zA + (n16)      * 64 + 32 + quad * 8);
    bf16x8 a10 = *(const bf16x8*)(zA + (16 + n16) * 64 +      quad * 8);
    bf16x8 a11 = *(const bf16x8*)(zA + (16 + n16) * 64 + 32 + quad * 8);
    bf16x8 b0  = *(const bf16x8*)(twB + g * 64 +      quad * 8);
    bf16x8 b1  = *(const bf16x8*)(twB + g * 64 + 32 + quad * 8);

    f32x4 d0 = {0.f, 0.f, 0.f, 0.f};
    f32x4 d1 = {0.f, 0.f, 0.f, 0.f};
    d0 = __builtin_amdgcn_mfma_f32_16x16x32_bf16(a00, b0, d0, 0, 0, 0);
    d0 = __builtin_amdgcn_mfma_f32_16x16x32_bf16(a01, b1, d0, 0, 0, 0);
    d1 = __builtin_amdgcn_mfma_f32_16x16x32_bf16(a10, b0, d1, 0, 0, 0);
    d1 = __builtin_amdgcn_mfma_f32_16x16x32_bf16(a11, b1, d1, 0, 0, 0);

    const float tbg = tb[g];
    float* ob = out + (size_t)b * NTC + g * 32;   // out[b][g][t]
    {
        float4 v;                                  // mtile 0: t = quad*4..+3
        v.x = d0[0] + tbg + hl[(quad * 4 + 0) * 65 + g];
        v.y = d0[1] + tbg + hl[(quad * 4 + 1) * 65 + g];
        v.z = d0[2] + tbg + hl[(quad * 4 + 2) * 65 + g];
        v.w = d0[3] + tbg + hl[(quad * 4 + 3) * 65 + g];
        *(float4*)(ob + quad * 4) = v;
    }
    {
        float4 v;                                  // mtile 1: t = 16+quad*4..+3
        v.x = d1[0] + tbg + hl[(16 + quad * 4 + 0) * 65 + g];
        v.y = d1[1] + tbg + hl[(16 + quad * 4 + 1) * 65 + g];
        v.z = d1[2] + tbg + hl[(16 + quad * 4 + 2) * 65 + g];
        v.w = d1[3] + tbg + hl[(16 + quad * 4 + 3) * 65 + g];
        *(float4*)(ob + 16 + quad * 4) = v;
    }
}

// ---------------- hop 1: bf16 gather of z + MFMA; p1 stored int16 ----------
// R12 found bf16 p1 payload (8-bit mantissa at |p1|~30 => eps~0.125/elem)
// broke the threshold chain; fp32 fixed it at 8KB/node gather cost in hop2.
// This round: per-node-scaled int16 (eps <= max|p1|/65534 ~ 1e-3/elem, ~100x
// tighter than the failing bf16) at HALF the hop2 gather bytes.
__global__ __launch_bounds__(256, 6)
void k_hop1(const unsigned short* __restrict__ p_in, const int* __restrict__ rowp,
            const int* __restrict__ csrs, const float* __restrict__ csrw,
            const unsigned short* __restrict__ twB,
            unsigned short* __restrict__ p1q, float* __restrict__ p1scl,
            float* __restrict__ out)
{
    __shared__ __align__(16) unsigned short pA[32 * 64];   // bf16 p1, 4KB
    __shared__ float mred[4];
    const int d = blockIdx.x, j = threadIdx.x;
    const int beg = rowp[d], end = rowp[d + 1];
    float acc[8];
#pragma unroll
    for (int r = 0; r < 8; ++r) acc[r] = 0.f;
    int e = beg;
    for (; e + 4 <= end; e += 4) {                // 4 gathers in flight
        int s0 = csrs[e],  s1 = csrs[e+1], s2 = csrs[e+2], s3 = csrs[e+3];
        float w0 = csrw[e], w1 = csrw[e+1], w2 = csrw[e+2], w3 = csrw[e+3];
        uint4 v0 = ((const uint4*)(p_in + (size_t)s0 * NTC))[j];  // 16B = 8 bf16
        uint4 v1 = ((const uint4*)(p_in + (size_t)s1 * NTC))[j];
        uint4 v2 = ((const uint4*)(p_in + (size_t)s2 * NTC))[j];
        uint4 v3 = ((const uint4*)(p_in + (size_t)s3 * NTC))[j];
        accv8(acc, v0, w0); accv8(acc, v1, w1);
        accv8(acc, v2, w2); accv8(acc, v3, w3);
    }
    for (; e < end; ++e) {
        int s0 = csrs[e];
        float w0 = csrw[e];
        uint4 v0 = ((const uint4*)(p_in + (size_t)s0 * NTC))[j];
        accv8(acc, v0, w0);
    }

    // ---- per-node max|p1| reduce (for int16 scale) ----
    const int lane = j & 63, w = j >> 6;
    float m = 0.f;
#pragma unroll
    for (int r = 0; r < 8; ++r) m = fmaxf(m, fabsf(acc[r]));
#pragma unroll
    for (int off = 32; off > 0; off >>= 1)
        m = fmaxf(m, __shfl_down(m, off, 64));
    if (lane == 0) mred[w] = m;
    __syncthreads();
    const float mv = fmaxf(fmaxf(mred[0], mred[1]), fmaxf(mred[2], mred[3]));
    const float inv = (mv > 0.f) ? (32767.f / mv) : 0.f;
    if (j == 0) p1scl[d] = mv * (1.f / 32767.f);

    {   // int16 p1 store: thread j owns elems 8j..8j+7 of [t][c] row-major
        uint4 qv;
        qv.x = pkq2(acc[0], acc[1], inv);
        qv.y = pkq2(acc[2], acc[3], inv);
        qv.z = pkq2(acc[4], acc[5], inv);
        qv.w = pkq2(acc[6], acc[7], inv);
        ((uint4*)(p1q + (size_t)d * NTC))[j] = qv;
    }
    uint4 pv;
    pv.x = pk2(acc[0], acc[1]); pv.y = pk2(acc[2], acc[3]);
    pv.z = pk2(acc[4], acc[5]); pv.w = pk2(acc[6], acc[7]);
    ((uint4*)pA)[j] = pv;                         // pA[t][c], t=j>>3
    __syncthreads();

    const int n16 = lane & 15, quad = lane >> 4;
    const int g = w * 16 + n16;

    bf16x8 a00 = *(const bf16x8*)(pA + (n16)      * 64 +      quad * 8);
    bf16x8 a01 = *(const bf16x8*)(pA + (n16)      * 64 + 32 + quad * 8);
    bf16x8 a10 = *(const bf16x8*)(pA + (16 + n16) * 64 +      quad * 8);
    bf16x8 a11 = *(const bf16x8*)(pA + (16 + n16) * 64 + 32 + quad * 8);
    bf16x8 b0  = *(const bf16x8*)(twB + g * 64 +      quad * 8);
    bf16x8 b1  = *(const bf16x8*)(twB + g * 64 + 32 + quad * 8);

    f32x4 d0 = {0.f, 0.f, 0.f, 0.f};
    f32x4 d1 = {0.f, 0.f, 0.f, 0.f};
    d0 = __builtin_amdgcn_mfma_f32_16x16x32_bf16(a00, b0, d0, 0, 0, 0);
    d0 = __builtin_amdgcn_mfma_f32_16x16x32_bf16(a01, b1, d0, 0, 0, 0);
    d1 = __builtin_amdgcn_mfma_f32_16x16x32_bf16(a10, b0, d1, 0, 0, 0);
    d1 = __builtin_amdgcn_mfma_f32_16x16x32_bf16(a11, b1, d1, 0, 0, 0);

    float* ob = out + (size_t)d * NTC + g * 32;   // out[b][g][t], block owns d
    {
        float4 v = *(float4*)(ob + quad * 4);
        v.x += d0[0]; v.y += d0[1]; v.z += d0[2]; v.w += d0[3];
        *(float4*)(ob + quad * 4) = v;
    }
    {
        float4 v = *(float4*)(ob + 16 + quad * 4);
        v.x += d1[0]; v.y += d1[1]; v.z += d1[2]; v.w += d1[3];
        *(float4*)(ob + 16 + quad * 4) = v;
    }
}

// ---------------- hop 2: int16 gather + FP32 LDS matmul --------------------
// Gather payload is per-node-scaled int16 (scale folded into edge weight);
// aggregation and the W2 matmul stay fp32 (the precision-critical path).
__global__ __launch_bounds__(256, 6)
void k_hop2(const unsigned short* __restrict__ p1q, const float* __restrict__ p1scl,
            const int* __restrict__ rowp, const int* __restrict__ csrs,
            const float* __restrict__ csrw, const float* __restrict__ tw,
            float* __restrict__ out)
{
    __shared__ float pl[32 * 65];
    __shared__ __align__(16) float W[64 * 64];
    const int d = blockIdx.x, j = threadIdx.x;
#pragma unroll
    for (int r = 0; r < 16; ++r) { int idx = j + r * 256; W[idx] = tw[idx]; }
    const int beg = rowp[d], end = rowp[d + 1];
    float acc[8];
#pragma unroll
    for (int r = 0; r < 8; ++r) acc[r] = 0.f;
    int e = beg;
    for (; e + 4 <= end; e += 4) {                // 4 gathers in flight (16B each)
        int s0 = csrs[e],  s1 = csrs[e+1], s2 = csrs[e+2], s3 = csrs[e+3];
        float w0 = csrw[e]   * p1scl[s0];
        float w1 = csrw[e+1] * p1scl[s1];
        float w2 = csrw[e+2] * p1scl[s2];
        float w3 = csrw[e+3] * p1scl[s3];
        uint4 v0 = ((const uint4*)(p1q + (size_t)s0 * NTC))[j];  // 16B = 8 int16
        uint4 v1 = ((const uint4*)(p1q + (size_t)s1 * NTC))[j];
        uint4 v2 = ((const uint4*)(p1q + (size_t)s2 * NTC))[j];
        uint4 v3 = ((const uint4*)(p1q + (size_t)s3 * NTC))[j];
        acci16(acc, v0, w0); acci16(acc, v1, w1);
        acci16(acc, v2, w2); acci16(acc, v3, w3);
    }
    for (; e < end; ++e) {
        int s0 = csrs[e];
        float w0 = csrw[e] * p1scl[s0];
        uint4 v0 = ((const uint4*)(p1q + (size_t)s0 * NTC))[j];
        acci16(acc, v0, w0);
    }
    {
        int tt = j >> 3, c0 = (j & 7) * 8;        // thread owns elems j*8..+7
        float* q = &pl[tt * 65 + c0];
#pragma unroll
        for (int s = 0; s < 8; ++s) q[s] = acc[s];
    }
    __syncthreads();
    const int t = j & 31, gq = (j >> 5) * 8;
    float accm[8];
#pragma unroll
    for (int r = 0; r < 8; ++r) accm[r] = 0.f;
    for (int f = 0; f < 64; ++f) {
        float pv = pl[t * 65 + f];
        const float4* Wr = (const float4*)&W[f * 64 + gq];
        float4 wa = Wr[0], wb = Wr[1];
        accm[0] += pv*wa.x; accm[1] += pv*wa.y; accm[2] += pv*wa.z; accm[3] += pv*wa.w;
        accm[4] += pv*wb.x; accm[5] += pv*wb.y; accm[6] += pv*wb.z; accm[7] += pv*wb.w;
    }
    float* ob = out + (size_t)d * NTC;
#pragma unroll
    for (int r = 0; r < 8; ++r)
        ob[(gq + r) * 32 + t] += accm[r];         // block owns node d: safe RMW
}

// ---------------- launch ----------------
// workspace floats:
//   [0, 4194304)          h_in [b][t][c] fp32
//   [4194304, 6291456)    p1q int16 [b][t][c] (ushort, 8MB)
//   [6291456, 6293504)    p1scl [b] fp32 (8KB)
//   [8388608, 10485760)   z_bf16 [b][t][c] (ushort, 8MB)
//   [10485760, +256)      stats (scale[64]@128, shift[64]@192)
//   [10486016, +6144)     wAb (bf16 conv A-layout, 24KB)
//   [10492160, +6144)     twB (bf16 tag W^T B-layout, 24KB)
//   [10498304, +262144)   partials [b][128]
//   [10760448, ...)       ints: mode(4) hist(2048) rowp(2052) cur(2048)
//                               csrs(32768) csrw(32768)      (~43 MiB total)
extern "C" void kernel_launch(void* const* d_in, const int* in_sizes, int n_in,
                              void* d_out, int out_size, void* d_ws, size_t ws_size,
                              hipStream_t stream)
{
    const float* x  = (const float*)d_in[0];
    const int*   ei = (const int*)  d_in[1];
    const float* ew = (const float*)d_in[2];
    const float* cw = (const float*)d_in[3];
    const float* cb = (const float*)d_in[4];
    const float* lg = (const float*)d_in[5];
    const float* lb = (const float*)d_in[6];
    const float* bg = (const float*)d_in[7];
    const float* bb = (const float*)d_in[8];
    const float* tw = (const float*)d_in[9];
    const float* tb = (const float*)d_in[10];
    float* out = (float*)d_out;
    float* ws  = (float*)d_ws;

    float*          h_in  = ws;
    unsigned short* p1q   = (unsigned short*)(ws + 4194304);
    float*          p1scl = ws + 6291456;
    unsigned short* zbf   = (unsigned short*)(ws + 8388608);
    float*          stats = ws + 10485760;
    unsigned short* wAb   = (unsigned short*)(ws + 10486016);
    unsigned short* twB   = (unsigned short*)(ws + 10492160);
    float*          parts = ws + 10498304;
    int*            ib    = (int*)(ws + 10760448);
    int*   mode  = ib;
    int*   hist  = ib + 4;
    int*   rowp  = ib + 2052;
    int*   cur   = ib + 4104;
    int*   csrs  = ib + 6152;
    float* csrw  = (float*)(ib + 38920);

    (void)hipMemsetAsync(ib, 0, 2052 * sizeof(int), stream);   // mode + hist

    k_detect <<<128, 256, 0, stream>>>(ei, mode);
    k_hist   <<<128, 256, 0, stream>>>(ei, mode, hist, cw, wAb, tw, twB);
    k_scan   <<<1,   256, 0, stream>>>(hist, rowp, cur);
    k_scat   <<<128, 256, 0, stream>>>(ei, ew, mode, cur, csrs, csrw);
    k_convln <<<NB,  256, 0, stream>>>(x, wAb, cb, lg, lb, h_in, parts);
    k_bnred  <<<64,  256, 0, stream>>>(parts, bg, bb, stats);
    k_zw0    <<<NB,  256, 0, stream>>>(h_in, stats, twB, tb, zbf, out);
    k_hop1   <<<NB,  256, 0, stream>>>(zbf, rowp, csrs, csrw, twB + 4096, p1q, p1scl, out);
    k_hop2   <<<NB,  256, 0, stream>>>(p1q, p1scl, rowp, csrs, csrw, tw + 8192, out);
}

// Round 2
// 170.090 us; speedup vs baseline: 1.1456x; 1.0568x over previous
//
#include <hip/hip_runtime.h>
#include <cstddef>

// B=2048, C_IN=C_OUT=64, T=32, E=32768, K_HOPS=2, KSIZE=3
#define NB   2048
#define NE   32768
#define NTC  2048      // T*C elems per node
#define SLOPE_F 0.01f
#define EPS_F   1e-5f

typedef short bf16x8 __attribute__((ext_vector_type(8)));
typedef float f32x4  __attribute__((ext_vector_type(4)));

// bf16 helpers (manual, RNE pack)
__device__ __forceinline__ unsigned short f2bf(float f) {
    unsigned u = __builtin_bit_cast(unsigned, f);
    u += 0x7FFF + ((u >> 16) & 1);
    return (unsigned short)(u >> 16);
}
__device__ __forceinline__ float bflo(unsigned v) {
    return __builtin_bit_cast(float, v << 16);
}
__device__ __forceinline__ float bfhi(unsigned v) {
    return __builtin_bit_cast(float, v & 0xFFFF0000u);
}
__device__ __forceinline__ unsigned pk2(float lo, float hi) {
    return (unsigned)f2bf(lo) | ((unsigned)f2bf(hi) << 16);
}
// unpack-accumulate 8 bf16 lanes of a uint4 into acc[0..7]
__device__ __forceinline__ void accv8(float* acc, const uint4& v, float wt) {
    acc[0] += wt * bflo(v.x); acc[1] += wt * bfhi(v.x);
    acc[2] += wt * bflo(v.y); acc[3] += wt * bfhi(v.y);
    acc[4] += wt * bflo(v.z); acc[5] += wt * bfhi(v.z);
    acc[6] += wt * bflo(v.w); acc[7] += wt * bfhi(v.w);
}
// unpack-accumulate 8 int16 lanes of a uint4 into acc[0..7] (wt has scale folded)
__device__ __forceinline__ void acci16(float* acc, const uint4& v, float wt) {
    acc[0] += wt * (float)(short)(v.x & 0xFFFFu); acc[1] += wt * (float)(short)(v.x >> 16);
    acc[2] += wt * (float)(short)(v.y & 0xFFFFu); acc[3] += wt * (float)(short)(v.y >> 16);
    acc[4] += wt * (float)(short)(v.z & 0xFFFFu); acc[5] += wt * (float)(short)(v.z >> 16);
    acc[6] += wt * (float)(short)(v.w & 0xFFFFu); acc[7] += wt * (float)(short)(v.w >> 16);
}
__device__ __forceinline__ unsigned pkq2(float a, float b, float inv) {
    int qa = __float2int_rn(a * inv);
    int qb = __float2int_rn(b * inv);
    return ((unsigned)qa & 0xFFFFu) | ((unsigned)qb << 16);
}

// ---------------- edge-index width handling (per-wave ballot detect) -------
// int64 layout: high words ei[2e+1] are all 0 (node ids < 2048).
// int32 layout: 64 sampled ids all zero has P = 2048^-64 ~ 0.
// So a wave-wide ballot over its own 64 samples decides the mode locally;
// no separate detect kernel, no global mode flag.
__device__ __forceinline__ int edge_src(const int* ei, int m, int e) {
    return m ? ei[e] : ei[2 * e];
}
__device__ __forceinline__ int edge_dst(const int* ei, int m, int e) {
    return m ? ei[NE + e] : ei[2 * (NE + e)];
}

// hist + weight packs:
//   blocks 0..47:  wAb[(kk*64+o)*64+i] = bf16 w[o][i][kk]     (conv A-layout)
//   blocks 48..95: twB[m][g*64+k]      = bf16 tw[m][k][g]     (tag B-layout, W^T)
__global__ __launch_bounds__(256)
void k_hist(const int* __restrict__ ei, int* __restrict__ hist,
            const float* __restrict__ cw, unsigned short* __restrict__ wAb,
            const float* __restrict__ tw, unsigned short* __restrict__ twB)
{
    int e = blockIdx.x * 256 + threadIdx.x;
    unsigned long long bal = __ballot(ei[2 * e + 1] != 0);
    int m = (bal != 0ull) ? 1 : 0;
    atomicAdd(&hist[edge_dst(ei, m, e)], 1);
    if (blockIdx.x < 48) {
        int idx = e;                      // 0..12287
        int kk = idx >> 12, o = (idx >> 6) & 63, i = idx & 63;
        wAb[idx] = f2bf(cw[o * 192 + i * 3 + kk]);
    } else if (blockIdx.x < 96) {
        int idx = e - 48 * 256;           // 0..12287
        int mm = idx >> 12, rem = idx & 4095;
        int g = rem >> 6, k = rem & 63;
        twB[idx] = f2bf(tw[mm * 4096 + k * 64 + g]);
    }
}

// single block: CSR row-pointer scan
__global__ __launch_bounds__(256)
void k_scan(const int* __restrict__ hist, int* __restrict__ rowp, int* __restrict__ cur)
{
    __shared__ int part[256];
    int j = threadIdx.x;
    int loc[8]; int s = 0;
#pragma unroll
    for (int r = 0; r < 8; ++r) { loc[r] = hist[j * 8 + r]; s += loc[r]; }
    part[j] = s;
    __syncthreads();
    for (int off = 1; off < 256; off <<= 1) {
        int v = (j >= off) ? part[j - off] : 0;
        __syncthreads();
        part[j] += v;
        __syncthreads();
    }
    int excl = part[j] - s;
#pragma unroll
    for (int r = 0; r < 8; ++r) {
        rowp[j * 8 + r] = excl;
        cur [j * 8 + r] = excl;
        excl += loc[r];
    }
    if (j == 255) rowp[2048] = excl;  // == NE
}

__global__ __launch_bounds__(256)
void k_scat(const int* __restrict__ ei, const float* __restrict__ ew,
            int* __restrict__ cur, int* __restrict__ csrs, float* __restrict__ csrw)
{
    int e = blockIdx.x * 256 + threadIdx.x;
    unsigned long long bal = __ballot(ei[2 * e + 1] != 0);
    int m = (bal != 0ull) ? 1 : 0;
    int d = edge_dst(ei, m, e);
    int pos = atomicAdd(&cur[d], 1);
    csrs[pos] = edge_src(ei, m, e);
    csrw[pos] = ew[e];
}

// ---------------- conv1d (MFMA) + leaky + LayerNorm + BN partials ----------
__global__ __launch_bounds__(256, 4)
void k_convln(const float* __restrict__ x, const unsigned short* __restrict__ wAb,
              const float* __restrict__ cb, const float* __restrict__ lg,
              const float* __restrict__ lb, float* __restrict__ h_in,
              float* __restrict__ partials)
{
    __shared__ __align__(16) unsigned short xT[36 * 72];
    __shared__ float hT[32 * 65];
    __shared__ float red1[64], red2[64];
    __shared__ float wsum[8];
    __shared__ float bcast[2];

    const int b = blockIdx.x, j = threadIdx.x;
    const float* __restrict__ xg = x + (size_t)b * NTC;

    {   // stage x -> bf16 xT[t+2][i]; zero-pad rows 0,1,34,35
        unsigned* xTd = (unsigned*)xT;
        int t = j & 31, p = j >> 5;
#pragma unroll
        for (int r = 0; r < 4; ++r) {
            int i0 = (r * 8 + p) * 2;
            float v0 = xg[i0 * 32 + t];
            float v1 = xg[(i0 + 1) * 32 + t];
            xTd[(t + 2) * 36 + (i0 >> 1)] = pk2(v0, v1);
        }
        if (j < 72)       xTd[j] = 0u;
        else if (j < 144) xTd[1224 + (j - 72)] = 0u;   // rows 34,35
    }
    __syncthreads();

    const int lane = j & 63, w = j >> 6;
    const int n16 = lane & 15, quad = lane >> 4;

    bf16x8 afr[3][2];
#pragma unroll
    for (int kk = 0; kk < 3; ++kk)
#pragma unroll
        for (int s = 0; s < 2; ++s) {
            int off16 = (kk * 64 + w * 16 + n16) * 64 + s * 32 + quad * 8;
            afr[kk][s] = *(const bf16x8*)(wAb + off16);
        }

    f32x4 acc0 = {0.f, 0.f, 0.f, 0.f};
    f32x4 acc1 = {0.f, 0.f, 0.f, 0.f};
#pragma unroll
    for (int kk = 0; kk < 3; ++kk)
#pragma unroll
        for (int s = 0; s < 2; ++s) {
            bf16x8 b0 = *(const bf16x8*)(xT + (n16 + kk) * 72 + s * 32 + quad * 8);
            bf16x8 b1 = *(const bf16x8*)(xT + (16 + n16 + kk) * 72 + s * 32 + quad * 8);
            acc0 = __builtin_amdgcn_mfma_f32_16x16x32_bf16(afr[kk][s], b0, acc0, 0, 0, 0);
            acc1 = __builtin_amdgcn_mfma_f32_16x16x32_bf16(afr[kk][s], b1, acc1, 0, 0, 0);
        }

    float vals[2][4];
    float s1 = 0.f, s2 = 0.f;
#pragma unroll
    for (int r = 0; r < 4; ++r) {
        float cbv = cb[w * 16 + quad * 4 + r];
        float v0 = acc0[r] + cbv;
        float v1 = acc1[r] + cbv;
        v0 = (v0 >= 0.f) ? v0 : SLOPE_F * v0;
        v1 = (v1 >= 0.f) ? v1 : SLOPE_F * v1;
        vals[0][r] = v0; vals[1][r] = v1;
        s1 += v0 + v1; s2 += v0 * v0 + v1 * v1;
    }
#pragma unroll
    for (int off = 32; off > 0; off >>= 1) {
        s1 += __shfl_down(s1, off, 64);
        s2 += __shfl_down(s2, off, 64);
    }
    if (lane == 0) { wsum[w] = s1; wsum[4 + w] = s2; }
    __syncthreads();
    if (j == 0) {
        float S1 = wsum[0] + wsum[1] + wsum[2] + wsum[3];
        float S2 = wsum[4] + wsum[5] + wsum[6] + wsum[7];
        float mu  = S1 * (1.f / 2048.f);
        float var = S2 * (1.f / 2048.f) - mu * mu;
        bcast[0] = mu;
        bcast[1] = rsqrtf(var + EPS_F);
    }
    __syncthreads();
    const float mu = bcast[0], rs = bcast[1];
    float po1[4] = {0.f, 0.f, 0.f, 0.f}, po2[4] = {0.f, 0.f, 0.f, 0.f};
#pragma unroll
    for (int nt = 0; nt < 2; ++nt) {
        int t = nt * 16 + n16;
#pragma unroll
        for (int r = 0; r < 4; ++r) {
            int o = w * 16 + quad * 4 + r;
            float h = (vals[nt][r] - mu) * rs * lg[o * 32 + t] + lb[o * 32 + t];
            hT[t * 65 + o] = h;
            po1[r] += h; po2[r] += h * h;
        }
    }
#pragma unroll
    for (int off = 8; off > 0; off >>= 1) {
#pragma unroll
        for (int r = 0; r < 4; ++r) {
            po1[r] += __shfl_down(po1[r], off, 16);
            po2[r] += __shfl_down(po2[r], off, 16);
        }
    }
    if (n16 == 0) {
#pragma unroll
        for (int r = 0; r < 4; ++r) {
            int o = w * 16 + quad * 4 + r;
            red1[o] = po1[r];
            red2[o] = po2[r];
        }
    }
    __syncthreads();
    float* hb = h_in + (size_t)b * NTC;
#pragma unroll
    for (int r = 0; r < 8; ++r) {                  // coalesced h_in store
        int idx = j + r * 256;
        hb[idx] = hT[(idx >> 6) * 65 + (idx & 63)];
    }
    float* pb_ = partials + (size_t)b * 128;       // coalesced 512B store
    if (j < 64)       pb_[j] = red1[j];
    else if (j < 128) pb_[j] = red2[j - 64];
}

// ---------------- reduce partials -> BN scale/shift ----------------
__global__ __launch_bounds__(256)
void k_bnred(const float* __restrict__ partials, const float* __restrict__ bg,
             const float* __restrict__ bb, float* __restrict__ stats)
{
    const int c = blockIdx.x, j = threadIdx.x;
    float s1 = 0.f, s2 = 0.f;
    for (int b = j; b < NB; b += 256) {
        const float* p = partials + (size_t)b * 128;
        s1 += p[c];
        s2 += p[64 + c];
    }
    __shared__ float r1[4], r2[4];
#pragma unroll
    for (int off = 32; off > 0; off >>= 1) {
        s1 += __shfl_down(s1, off, 64);
        s2 += __shfl_down(s2, off, 64);
    }
    if ((j & 63) == 0) { r1[j >> 6] = s1; r2[j >> 6] = s2; }
    __syncthreads();
    if (j == 0) {
        float S1 = r1[0] + r1[1] + r1[2] + r1[3];
        float S2 = r2[0] + r2[1] + r2[2] + r2[3];
        const float inv_n = 1.f / 65536.f;
        float mu  = S1 * inv_n;
        float var = S2 * inv_n - mu * mu;
        float rs  = rsqrtf(var + EPS_F);
        float sc  = bg[c] * rs;
        stats[128 + c] = sc;
        stats[192 + c] = bb[c] - mu * sc;
    }
}

// ---------------- z = leaky(BN(h)) -> bf16, pure stream --------------------
// (W0 matmul + out init moved into k_hop1; this is now 25 MB of streaming.)
__global__ __launch_bounds__(256)
void k_zlite(const float* __restrict__ h_in, const float* __restrict__ stats,
             unsigned short* __restrict__ zb16)
{
    __shared__ float scs[64], shs[64];
    const int b = blockIdx.x, j = threadIdx.x;
    if (j < 64)        scs[j] = stats[128 + j];
    else if (j < 128)  shs[j - 64] = stats[192 + (j - 64)];
    __syncthreads();
    const float4* hb = (const float4*)(h_in + (size_t)b * NTC);
    float4 a = hb[2 * j], c4 = hb[2 * j + 1];     // elems 8j..8j+7 (t*64+c order)
    const int c0 = (j * 8) & 63;
    float z0 = a.x  * scs[c0+0] + shs[c0+0];
    float z1 = a.y  * scs[c0+1] + shs[c0+1];
    float z2 = a.z  * scs[c0+2] + shs[c0+2];
    float z3 = a.w  * scs[c0+3] + shs[c0+3];
    float z4 = c4.x * scs[c0+4] + shs[c0+4];
    float z5 = c4.y * scs[c0+5] + shs[c0+5];
    float z6 = c4.z * scs[c0+6] + shs[c0+6];
    float z7 = c4.w * scs[c0+7] + shs[c0+7];
    z0 = (z0 >= 0.f) ? z0 : SLOPE_F * z0;  z1 = (z1 >= 0.f) ? z1 : SLOPE_F * z1;
    z2 = (z2 >= 0.f) ? z2 : SLOPE_F * z2;  z3 = (z3 >= 0.f) ? z3 : SLOPE_F * z3;
    z4 = (z4 >= 0.f) ? z4 : SLOPE_F * z4;  z5 = (z5 >= 0.f) ? z5 : SLOPE_F * z5;
    z6 = (z6 >= 0.f) ? z6 : SLOPE_F * z6;  z7 = (z7 >= 0.f) ? z7 : SLOPE_F * z7;
    uint4 q;
    q.x = pk2(z0, z1); q.y = pk2(z2, z3); q.z = pk2(z4, z5); q.w = pk2(z6, z7);
    ((uint4*)(zb16 + (size_t)b * NTC))[j] = q;
}

// ---------------- hop 1: gather z (bf16) + fused out = h + z@W0 + p1@W1 ----
// 8-deep gather MLP; out written once (no RMW read); p1 stored int16
// (per-node scale, eps <= max|p1|/32767 ~ 1e-3 -- R1-verified numerics).
__global__ __launch_bounds__(256, 4)
void k_hop1(const unsigned short* __restrict__ p_in, const float* __restrict__ h_in,
            const int* __restrict__ rowp, const int* __restrict__ csrs,
            const float* __restrict__ csrw, const unsigned short* __restrict__ twB,
            const float* __restrict__ tb,
            unsigned short* __restrict__ p1q, float* __restrict__ p1scl,
            float* __restrict__ out)
{
    __shared__ __align__(16) unsigned short pA[32 * 64];   // bf16 p1, 4KB
    __shared__ __align__(16) unsigned short zA[32 * 64];   // bf16 z[d], 4KB
    __shared__ float hl[32 * 65];                          // fp32 h residual
    __shared__ float mred[4];
    const int d = blockIdx.x, j = threadIdx.x;

    {   // stage own z row (for z@W0) and h row (residual)
        uint4 zv = ((const uint4*)(p_in + (size_t)d * NTC))[j];
        ((uint4*)zA)[j] = zv;
        const float4* hb4 = (const float4*)(h_in + (size_t)d * NTC);
        float4 h0 = hb4[2 * j], h1 = hb4[2 * j + 1];
        int tt = j >> 3, c0 = (j & 7) * 8;
        float* q = &hl[tt * 65 + c0];
        q[0] = h0.x; q[1] = h0.y; q[2] = h0.z; q[3] = h0.w;
        q[4] = h1.x; q[5] = h1.y; q[6] = h1.z; q[7] = h1.w;
    }

    const int beg = rowp[d], end = rowp[d + 1];
    float acc[8];
#pragma unroll
    for (int r = 0; r < 8; ++r) acc[r] = 0.f;
    int e = beg;
    for (; e + 8 <= end; e += 8) {                // 8 gathers in flight
        int   s0 = csrs[e],   s1 = csrs[e+1], s2 = csrs[e+2], s3 = csrs[e+3];
        int   s4 = csrs[e+4], s5 = csrs[e+5], s6 = csrs[e+6], s7 = csrs[e+7];
        float w0 = csrw[e],   w1 = csrw[e+1], w2 = csrw[e+2], w3 = csrw[e+3];
        float w4 = csrw[e+4], w5 = csrw[e+5], w6 = csrw[e+6], w7 = csrw[e+7];
        uint4 v0 = ((const uint4*)(p_in + (size_t)s0 * NTC))[j];
        uint4 v1 = ((const uint4*)(p_in + (size_t)s1 * NTC))[j];
        uint4 v2 = ((const uint4*)(p_in + (size_t)s2 * NTC))[j];
        uint4 v3 = ((const uint4*)(p_in + (size_t)s3 * NTC))[j];
        uint4 v4 = ((const uint4*)(p_in + (size_t)s4 * NTC))[j];
        uint4 v5 = ((const uint4*)(p_in + (size_t)s5 * NTC))[j];
        uint4 v6 = ((const uint4*)(p_in + (size_t)s6 * NTC))[j];
        uint4 v7 = ((const uint4*)(p_in + (size_t)s7 * NTC))[j];
        accv8(acc, v0, w0); accv8(acc, v1, w1);
        accv8(acc, v2, w2); accv8(acc, v3, w3);
        accv8(acc, v4, w4); accv8(acc, v5, w5);
        accv8(acc, v6, w6); accv8(acc, v7, w7);
    }
    for (; e + 2 <= end; e += 2) {
        int s0 = csrs[e],  s1 = csrs[e+1];
        float w0 = csrw[e], w1 = csrw[e+1];
        uint4 v0 = ((const uint4*)(p_in + (size_t)s0 * NTC))[j];
        uint4 v1 = ((const uint4*)(p_in + (size_t)s1 * NTC))[j];
        accv8(acc, v0, w0); accv8(acc, v1, w1);
    }
    if (e < end) {
        int s0 = csrs[e];
        float w0 = csrw[e];
        uint4 v0 = ((const uint4*)(p_in + (size_t)s0 * NTC))[j];
        accv8(acc, v0, w0);
    }

    // ---- per-node max|p1| reduce (for int16 scale) ----
    const int lane = j & 63, w = j >> 6;
    float m = 0.f;
#pragma unroll
    for (int r = 0; r < 8; ++r) m = fmaxf(m, fabsf(acc[r]));
#pragma unroll
    for (int off = 32; off > 0; off >>= 1)
        m = fmaxf(m, __shfl_down(m, off, 64));
    if (lane == 0) mred[w] = m;
    __syncthreads();
    const float mv = fmaxf(fmaxf(mred[0], mred[1]), fmaxf(mred[2], mred[3]));
    const float inv = (mv > 0.f) ? (32767.f / mv) : 0.f;
    if (j == 0) p1scl[d] = mv * (1.f / 32767.f);

    {   // int16 p1 store: thread j owns elems 8j..8j+7 of [t][c] row-major
        uint4 qv;
        qv.x = pkq2(acc[0], acc[1], inv);
        qv.y = pkq2(acc[2], acc[3], inv);
        qv.z = pkq2(acc[4], acc[5], inv);
        qv.w = pkq2(acc[6], acc[7], inv);
        ((uint4*)(p1q + (size_t)d * NTC))[j] = qv;
    }
    uint4 pv;
    pv.x = pk2(acc[0], acc[1]); pv.y = pk2(acc[2], acc[3]);
    pv.z = pk2(acc[4], acc[5]); pv.w = pk2(acc[6], acc[7]);
    ((uint4*)pA)[j] = pv;                         // pA[t][c], t=j>>3
    __syncthreads();

    const int n16 = lane & 15, quad = lane >> 4;
    const int g = w * 16 + n16;

    // A-frags: z (for W0) and p1 (for W1); B-frags: W0^T, W1^T
    bf16x8 za00 = *(const bf16x8*)(zA + (n16)      * 64 +      quad * 8);
    bf16x8 za01 = *(const bf16x8*)(zA + (n16)      * 64 + 32 + quad * 8);
    bf16x8 za10 = *(const bf16x8*)(zA + (16 + n16) * 64 +      quad * 8);
    bf16x8 za11 = *(const bf16x8*)(zA + (16 + n16) * 64 + 32 + quad * 8);
    bf16x8 pa00 = *(const bf16x8*)(pA + (n16)      * 64 +      quad * 8);
    bf16x8 pa01 = *(const bf16x8*)(pA + (n16)      * 64 + 32 + quad * 8);
    bf16x8 pa10 = *(const bf16x8*)(pA + (16 + n16) * 64 +      quad * 8);
    bf16x8 pa11 = *(const bf16x8*)(pA + (16 + n16) * 64 + 32 + quad * 8);
    bf16x8 b0w0 = *(const bf16x8*)(twB + g * 64 +      quad * 8);
    bf16x8 b1w0 = *(const bf16x8*)(twB + g * 64 + 32 + quad * 8);
    bf16x8 b0w1 = *(const bf16x8*)(twB + 4096 + g * 64 +      quad * 8);
    bf16x8 b1w1 = *(const bf16x8*)(twB + 4096 + g * 64 + 32 + quad * 8);

    f32x4 d0 = {0.f, 0.f, 0.f, 0.f};
    f32x4 d1 = {0.f, 0.f, 0.f, 0.f};
    d0 = __builtin_amdgcn_mfma_f32_16x16x32_bf16(za00, b0w0, d0, 0, 0, 0);
    d0 = __builtin_amdgcn_mfma_f32_16x16x32_bf16(za01, b1w0, d0, 0, 0, 0);
    d0 = __builtin_amdgcn_mfma_f32_16x16x32_bf16(pa00, b0w1, d0, 0, 0, 0);
    d0 = __builtin_amdgcn_mfma_f32_16x16x32_bf16(pa01, b1w1, d0, 0, 0, 0);
    d1 = __builtin_amdgcn_mfma_f32_16x16x32_bf16(za10, b0w0, d1, 0, 0, 0);
    d1 = __builtin_amdgcn_mfma_f32_16x16x32_bf16(za11, b1w0, d1, 0, 0, 0);
    d1 = __builtin_amdgcn_mfma_f32_16x16x32_bf16(pa10, b0w1, d1, 0, 0, 0);
    d1 = __builtin_amdgcn_mfma_f32_16x16x32_bf16(pa11, b1w1, d1, 0, 0, 0);

    const float tbg = tb[g];
    float* ob = out + (size_t)d * NTC + g * 32;   // out[b][g][t], pure store
    {
        float4 v;                                  // mtile 0: t = quad*4..+3
        v.x = d0[0] + tbg + hl[(quad * 4 + 0) * 65 + g];
        v.y = d0[1] + tbg + hl[(quad * 4 + 1) * 65 + g];
        v.z = d0[2] + tbg + hl[(quad * 4 + 2) * 65 + g];
        v.w = d0[3] + tbg + hl[(quad * 4 + 3) * 65 + g];
        *(float4*)(ob + quad * 4) = v;
    }
    {
        float4 v;                                  // mtile 1: t = 16+quad*4..+3
        v.x = d1[0] + tbg + hl[(16 + quad * 4 + 0) * 65 + g];
        v.y = d1[1] + tbg + hl[(16 + quad * 4 + 1) * 65 + g];
        v.z = d1[2] + tbg + hl[(16 + quad * 4 + 2) * 65 + g];
        v.w = d1[3] + tbg + hl[(16 + quad * 4 + 3) * 65 + g];
        *(float4*)(ob + 16 + quad * 4) = v;
    }
}

// ---------------- hop 2: int16 gather (8-deep) + FP32 LDS matmul -----------
// Aggregation and the W2 matmul stay fp32 (the precision-critical path).
__global__ __launch_bounds__(256, 4)
void k_hop2(const unsigned short* __restrict__ p1q, const float* __restrict__ p1scl,
            const int* __restrict__ rowp, const int* __restrict__ csrs,
            const float* __restrict__ csrw, const float* __restrict__ tw,
            float* __restrict__ out)
{
    __shared__ float pl[32 * 65];
    __shared__ __align__(16) float W[64 * 64];
    const int d = blockIdx.x, j = threadIdx.x;
#pragma unroll
    for (int r = 0; r < 16; ++r) { int idx = j + r * 256; W[idx] = tw[idx]; }
    const int beg = rowp[d], end = rowp[d + 1];
    float acc[8];
#pragma unroll
    for (int r = 0; r < 8; ++r) acc[r] = 0.f;
    int e = beg;
    for (; e + 8 <= end; e += 8) {                // 8 gathers in flight (16B each)
        int   s0 = csrs[e],   s1 = csrs[e+1], s2 = csrs[e+2], s3 = csrs[e+3];
        int   s4 = csrs[e+4], s5 = csrs[e+5], s6 = csrs[e+6], s7 = csrs[e+7];
        float w0 = csrw[e]   * p1scl[s0];
        float w1 = csrw[e+1] * p1scl[s1];
        float w2 = csrw[e+2] * p1scl[s2];
        float w3 = csrw[e+3] * p1scl[s3];
        float w4 = csrw[e+4] * p1scl[s4];
        float w5 = csrw[e+5] * p1scl[s5];
        float w6 = csrw[e+6] * p1scl[s6];
        float w7 = csrw[e+7] * p1scl[s7];
        uint4 v0 = ((const uint4*)(p1q + (size_t)s0 * NTC))[j];
        uint4 v1 = ((const uint4*)(p1q + (size_t)s1 * NTC))[j];
        uint4 v2 = ((const uint4*)(p1q + (size_t)s2 * NTC))[j];
        uint4 v3 = ((const uint4*)(p1q + (size_t)s3 * NTC))[j];
        uint4 v4 = ((const uint4*)(p1q + (size_t)s4 * NTC))[j];
        uint4 v5 = ((const uint4*)(p1q + (size_t)s5 * NTC))[j];
        uint4 v6 = ((const uint4*)(p1q + (size_t)s6 * NTC))[j];
        uint4 v7 = ((const uint4*)(p1q + (size_t)s7 * NTC))[j];
        acci16(acc, v0, w0); acci16(acc, v1, w1);
        acci16(acc, v2, w2); acci16(acc, v3, w3);
        acci16(acc, v4, w4); acci16(acc, v5, w5);
        acci16(acc, v6, w6); acci16(acc, v7, w7);
    }
    for (; e + 2 <= end; e += 2) {
        int s0 = csrs[e],  s1 = csrs[e+1];
        float w0 = csrw[e]   * p1scl[s0];
        float w1 = csrw[e+1] * p1scl[s1];
        uint4 v0 = ((const uint4*)(p1q + (size_t)s0 * NTC))[j];
        uint4 v1 = ((const uint4*)(p1q + (size_t)s1 * NTC))[j];
        acci16(acc, v0, w0); acci16(acc, v1, w1);
    }
    if (e < end) {
        int s0 = csrs[e];
        float w0 = csrw[e] * p1scl[s0];
        uint4 v0 = ((const uint4*)(p1q + (size_t)s0 * NTC))[j];
        acci16(acc, v0, w0);
    }
    {
        int tt = j >> 3, c0 = (j & 7) * 8;        // thread owns elems j*8..+7
        float* q = &pl[tt * 65 + c0];
#pragma unroll
        for (int s = 0; s < 8; ++s) q[s] = acc[s];
    }
    __syncthreads();
    const int t = j & 31, gq = (j >> 5) * 8;
    float accm[8];
#pragma unroll
    for (int r = 0; r < 8; ++r) accm[r] = 0.f;
    for (int f = 0; f < 64; ++f) {
        float pv = pl[t * 65 + f];
        const float4* Wr = (const float4*)&W[f * 64 + gq];
        float4 wa = Wr[0], wb = Wr[1];
        accm[0] += pv*wa.x; accm[1] += pv*wa.y; accm[2] += pv*wa.z; accm[3] += pv*wa.w;
        accm[4] += pv*wb.x; accm[5] += pv*wb.y; accm[6] += pv*wb.z; accm[7] += pv*wb.w;
    }
    float* ob = out + (size_t)d * NTC;
#pragma unroll
    for (int r = 0; r < 8; ++r)
        ob[(gq + r) * 32 + t] += accm[r];         // block owns node d: safe RMW
}

// ---------------- launch ----------------
// workspace floats:
//   [0, 4194304)          h_in [b][t][c] fp32
//   [4194304, 6291456)    p1q int16 [b][t][c] (ushort, 8MB)
//   [6291456, 6293504)    p1scl [b] fp32 (8KB)
//   [8388608, 10485760)   z_bf16 [b][t][c] (ushort, 8MB)
//   [10485760, +256)      stats (scale[64]@128, shift[64]@192)
//   [10486016, +6144)     wAb (bf16 conv A-layout, 24KB)
//   [10492160, +6144)     twB (bf16 tag W^T B-layout, 24KB)
//   [10498304, +262144)   partials [b][128]
//   [10760448, ...)       ints: hist(2048) rowp(2049+pad) cur(2048)
//                               csrs(32768) csrw(32768)
extern "C" void kernel_launch(void* const* d_in, const int* in_sizes, int n_in,
                              void* d_out, int out_size, void* d_ws, size_t ws_size,
                              hipStream_t stream)
{
    const float* x  = (const float*)d_in[0];
    const int*   ei = (const int*)  d_in[1];
    const float* ew = (const float*)d_in[2];
    const float* cw = (const float*)d_in[3];
    const float* cb = (const float*)d_in[4];
    const float* lg = (const float*)d_in[5];
    const float* lb = (const float*)d_in[6];
    const float* bg = (const float*)d_in[7];
    const float* bb = (const float*)d_in[8];
    const float* tw = (const float*)d_in[9];
    const float* tb = (const float*)d_in[10];
    float* out = (float*)d_out;
    float* ws  = (float*)d_ws;

    float*          h_in  = ws;
    unsigned short* p1q   = (unsigned short*)(ws + 4194304);
    float*          p1scl = ws + 6291456;
    unsigned short* zbf   = (unsigned short*)(ws + 8388608);
    float*          stats = ws + 10485760;
    unsigned short* wAb   = (unsigned short*)(ws + 10486016);
    unsigned short* twB   = (unsigned short*)(ws + 10492160);
    float*          parts = ws + 10498304;
    int*            ib    = (int*)(ws + 10760448);
    int*   hist  = ib;
    int*   rowp  = ib + 2048;
    int*   cur   = ib + 4100;
    int*   csrs  = ib + 6148;
    float* csrw  = (float*)(ib + 38916);

    (void)hipMemsetAsync(hist, 0, 2048 * sizeof(int), stream);

    k_hist   <<<128, 256, 0, stream>>>(ei, hist, cw, wAb, tw, twB);
    k_scan   <<<1,   256, 0, stream>>>(hist, rowp, cur);
    k_scat   <<<128, 256, 0, stream>>>(ei, ew, cur, csrs, csrw);
    k_convln <<<NB,  256, 0, stream>>>(x, wAb, cb, lg, lb, h_in, parts);
    k_bnred  <<<64,  256, 0, stream>>>(parts, bg, bb, stats);
    k_zlite  <<<NB,  256, 0, stream>>>(h_in, stats, zbf);
    k_hop1   <<<NB,  256, 0, stream>>>(zbf, h_in, rowp, csrs, csrw, twB, tb, p1q, p1scl, out);
    k_hop2   <<<NB,  256, 0, stream>>>(p1q, p1scl, rowp, csrs, csrw, tw + 8192, out);
}

// Round 3
// 164.880 us; speedup vs baseline: 1.1818x; 1.0316x over previous
//
#include <hip/hip_runtime.h>
#include <cstddef>

// B=2048, C_IN=C_OUT=64, T=32, E=32768, K_HOPS=2, KSIZE=3
#define NB   2048
#define NE   32768
#define NTC  2048      // T*C elems per node
#define SLOPE_F 0.01f
#define EPS_F   1e-5f

typedef short bf16x8 __attribute__((ext_vector_type(8)));
typedef float f32x4  __attribute__((ext_vector_type(4)));

// bf16 helpers (manual, RNE pack)
__device__ __forceinline__ unsigned short f2bf(float f) {
    unsigned u = __builtin_bit_cast(unsigned, f);
    u += 0x7FFF + ((u >> 16) & 1);
    return (unsigned short)(u >> 16);
}
__device__ __forceinline__ float bflo(unsigned v) {
    return __builtin_bit_cast(float, v << 16);
}
__device__ __forceinline__ float bfhi(unsigned v) {
    return __builtin_bit_cast(float, v & 0xFFFF0000u);
}
__device__ __forceinline__ unsigned pk2(float lo, float hi) {
    return (unsigned)f2bf(lo) | ((unsigned)f2bf(hi) << 16);
}
// unpack-accumulate 8 bf16 lanes of a uint4 into acc[0..7]
__device__ __forceinline__ void accv8(float* acc, const uint4& v, float wt) {
    acc[0] += wt * bflo(v.x); acc[1] += wt * bfhi(v.x);
    acc[2] += wt * bflo(v.y); acc[3] += wt * bfhi(v.y);
    acc[4] += wt * bflo(v.z); acc[5] += wt * bfhi(v.z);
    acc[6] += wt * bflo(v.w); acc[7] += wt * bfhi(v.w);
}
// unpack-accumulate 8 int16 lanes of a uint4 into acc[0..7] (wt has scale folded)
__device__ __forceinline__ void acci16(float* acc, const uint4& v, float wt) {
    acc[0] += wt * (float)(short)(v.x & 0xFFFFu); acc[1] += wt * (float)(short)(v.x >> 16);
    acc[2] += wt * (float)(short)(v.y & 0xFFFFu); acc[3] += wt * (float)(short)(v.y >> 16);
    acc[4] += wt * (float)(short)(v.z & 0xFFFFu); acc[5] += wt * (float)(short)(v.z >> 16);
    acc[6] += wt * (float)(short)(v.w & 0xFFFFu); acc[7] += wt * (float)(short)(v.w >> 16);
}
__device__ __forceinline__ unsigned pkq2(float a, float b, float inv) {
    int qa = __float2int_rn(a * inv);
    int qb = __float2int_rn(b * inv);
    return ((unsigned)qa & 0xFFFFu) | ((unsigned)qb << 16);
}

// ---------------- edge-index width handling (per-wave ballot detect) -------
// int64 layout: high words ei[2e+1] all 0 (ids < 2048). int32 layout:
// P(64 sampled ids all zero) = 2048^-64 ~ 0. Wave-local ballot decides.
__device__ __forceinline__ int edge_src(const int* ei, int m, int e) {
    return m ? ei[e] : ei[2 * e];
}
__device__ __forceinline__ int edge_dst(const int* ei, int m, int e) {
    return m ? ei[NE + e] : ei[2 * (NE + e)];
}

// ---------------- dispatch 1: zero hist + pack weights ---------------------
//   blocks 0..47:  wAb[(kk*64+o)*64+i] = bf16 w[o][i][kk]     (conv A-layout)
//   blocks 48..95: twB[m][g*64+k]      = bf16 tw[m][k][g]     (tag B-layout, W^T)
//   first 2048 flat threads: hist = 0   (replaces hipMemsetAsync)
__global__ __launch_bounds__(256)
void k_pre(int* __restrict__ hist, const float* __restrict__ cw,
           unsigned short* __restrict__ wAb, const float* __restrict__ tw,
           unsigned short* __restrict__ twB)
{
    int gid = blockIdx.x * 256 + threadIdx.x;
    if (gid < 2048) hist[gid] = 0;
    if (blockIdx.x < 48) {
        int idx = gid;                    // 0..12287
        int kk = idx >> 12, o = (idx >> 6) & 63, i = idx & 63;
        wAb[idx] = f2bf(cw[o * 192 + i * 3 + kk]);
    } else {                              // blocks 48..95
        int idx = gid - 48 * 256;         // 0..12287
        int mm = idx >> 12, rem = idx & 4095;
        int g = rem >> 6, k = rem & 63;
        twB[idx] = f2bf(tw[mm * 4096 + k * 64 + g]);
    }
}

// ---------------- dispatch 2: convln (blocks 0..2047) U hist (2048..2175) --
// conv1d (MFMA) + leaky + LayerNorm + BN partials; hist rides along since
// the CSR chain is independent of the conv chain.
__global__ __launch_bounds__(256, 4)
void k_main(const float* __restrict__ x, const unsigned short* __restrict__ wAb,
            const float* __restrict__ cb, const float* __restrict__ lg,
            const float* __restrict__ lb, float* __restrict__ h_in,
            float* __restrict__ partials,
            const int* __restrict__ ei, int* __restrict__ hist)
{
    if (blockIdx.x >= NB) {               // ---- hist part (whole blocks) ----
        int e = (blockIdx.x - NB) * 256 + threadIdx.x;
        unsigned long long bal = __ballot(ei[2 * e + 1] != 0);
        int m = (bal != 0ull) ? 1 : 0;
        atomicAdd(&hist[edge_dst(ei, m, e)], 1);
        return;
    }
    __shared__ __align__(16) unsigned short xT[36 * 72];
    __shared__ float hT[32 * 65];
    __shared__ float red1[64], red2[64];
    __shared__ float wsum[8];
    __shared__ float bcast[2];

    const int b = blockIdx.x, j = threadIdx.x;
    const float* __restrict__ xg = x + (size_t)b * NTC;

    {   // stage x -> bf16 xT[t+2][i]; zero-pad rows 0,1,34,35
        unsigned* xTd = (unsigned*)xT;
        int t = j & 31, p = j >> 5;
#pragma unroll
        for (int r = 0; r < 4; ++r) {
            int i0 = (r * 8 + p) * 2;
            float v0 = xg[i0 * 32 + t];
            float v1 = xg[(i0 + 1) * 32 + t];
            xTd[(t + 2) * 36 + (i0 >> 1)] = pk2(v0, v1);
        }
        if (j < 72)       xTd[j] = 0u;
        else if (j < 144) xTd[1224 + (j - 72)] = 0u;   // rows 34,35
    }
    __syncthreads();

    const int lane = j & 63, w = j >> 6;
    const int n16 = lane & 15, quad = lane >> 4;

    bf16x8 afr[3][2];
#pragma unroll
    for (int kk = 0; kk < 3; ++kk)
#pragma unroll
        for (int s = 0; s < 2; ++s) {
            int off16 = (kk * 64 + w * 16 + n16) * 64 + s * 32 + quad * 8;
            afr[kk][s] = *(const bf16x8*)(wAb + off16);
        }

    f32x4 acc0 = {0.f, 0.f, 0.f, 0.f};
    f32x4 acc1 = {0.f, 0.f, 0.f, 0.f};
#pragma unroll
    for (int kk = 0; kk < 3; ++kk)
#pragma unroll
        for (int s = 0; s < 2; ++s) {
            bf16x8 b0 = *(const bf16x8*)(xT + (n16 + kk) * 72 + s * 32 + quad * 8);
            bf16x8 b1 = *(const bf16x8*)(xT + (16 + n16 + kk) * 72 + s * 32 + quad * 8);
            acc0 = __builtin_amdgcn_mfma_f32_16x16x32_bf16(afr[kk][s], b0, acc0, 0, 0, 0);
            acc1 = __builtin_amdgcn_mfma_f32_16x16x32_bf16(afr[kk][s], b1, acc1, 0, 0, 0);
        }

    float vals[2][4];
    float s1 = 0.f, s2 = 0.f;
#pragma unroll
    for (int r = 0; r < 4; ++r) {
        float cbv = cb[w * 16 + quad * 4 + r];
        float v0 = acc0[r] + cbv;
        float v1 = acc1[r] + cbv;
        v0 = (v0 >= 0.f) ? v0 : SLOPE_F * v0;
        v1 = (v1 >= 0.f) ? v1 : SLOPE_F * v1;
        vals[0][r] = v0; vals[1][r] = v1;
        s1 += v0 + v1; s2 += v0 * v0 + v1 * v1;
    }
#pragma unroll
    for (int off = 32; off > 0; off >>= 1) {
        s1 += __shfl_down(s1, off, 64);
        s2 += __shfl_down(s2, off, 64);
    }
    if (lane == 0) { wsum[w] = s1; wsum[4 + w] = s2; }
    __syncthreads();
    if (j == 0) {
        float S1 = wsum[0] + wsum[1] + wsum[2] + wsum[3];
        float S2 = wsum[4] + wsum[5] + wsum[6] + wsum[7];
        float mu  = S1 * (1.f / 2048.f);
        float var = S2 * (1.f / 2048.f) - mu * mu;
        bcast[0] = mu;
        bcast[1] = rsqrtf(var + EPS_F);
    }
    __syncthreads();
    const float mu = bcast[0], rs = bcast[1];
    float po1[4] = {0.f, 0.f, 0.f, 0.f}, po2[4] = {0.f, 0.f, 0.f, 0.f};
#pragma unroll
    for (int nt = 0; nt < 2; ++nt) {
        int t = nt * 16 + n16;
#pragma unroll
        for (int r = 0; r < 4; ++r) {
            int o = w * 16 + quad * 4 + r;
            float h = (vals[nt][r] - mu) * rs * lg[o * 32 + t] + lb[o * 32 + t];
            hT[t * 65 + o] = h;
            po1[r] += h; po2[r] += h * h;
        }
    }
#pragma unroll
    for (int off = 8; off > 0; off >>= 1) {
#pragma unroll
        for (int r = 0; r < 4; ++r) {
            po1[r] += __shfl_down(po1[r], off, 16);
            po2[r] += __shfl_down(po2[r], off, 16);
        }
    }
    if (n16 == 0) {
#pragma unroll
        for (int r = 0; r < 4; ++r) {
            int o = w * 16 + quad * 4 + r;
            red1[o] = po1[r];
            red2[o] = po2[r];
        }
    }
    __syncthreads();
    float* hb = h_in + (size_t)b * NTC;
#pragma unroll
    for (int r = 0; r < 8; ++r) {                  // coalesced h_in store
        int idx = j + r * 256;
        hb[idx] = hT[(idx >> 6) * 65 + (idx & 63)];
    }
    float* pb_ = partials + (size_t)b * 128;       // coalesced 512B store
    if (j < 64)       pb_[j] = red1[j];
    else if (j < 128) pb_[j] = red2[j - 64];
}

// ---------------- dispatch 3: scan (block 0) U bnred (blocks 1..64) --------
__global__ __launch_bounds__(256)
void k_mid(const int* __restrict__ hist, int* __restrict__ rowp,
           int* __restrict__ cur, const float* __restrict__ partials,
           const float* __restrict__ bg, const float* __restrict__ bb,
           float* __restrict__ stats)
{
    __shared__ int part[256];
    __shared__ float r1[4], r2[4];
    const int j = threadIdx.x;
    if (blockIdx.x == 0) {                // ---- CSR row-pointer scan ----
        int loc[8]; int s = 0;
#pragma unroll
        for (int r = 0; r < 8; ++r) { loc[r] = hist[j * 8 + r]; s += loc[r]; }
        part[j] = s;
        __syncthreads();
        for (int off = 1; off < 256; off <<= 1) {
            int v = (j >= off) ? part[j - off] : 0;
            __syncthreads();
            part[j] += v;
            __syncthreads();
        }
        int excl = part[j] - s;
#pragma unroll
        for (int r = 0; r < 8; ++r) {
            rowp[j * 8 + r] = excl;
            cur [j * 8 + r] = excl;
            excl += loc[r];
        }
        if (j == 255) rowp[2048] = excl;  // == NE
        return;
    }
    // ---- BN partial reduce, c = blockIdx.x - 1 ----
    const int c = blockIdx.x - 1;
    float s1 = 0.f, s2 = 0.f;
    for (int b = j; b < NB; b += 256) {
        const float* p = partials + (size_t)b * 128;
        s1 += p[c];
        s2 += p[64 + c];
    }
#pragma unroll
    for (int off = 32; off > 0; off >>= 1) {
        s1 += __shfl_down(s1, off, 64);
        s2 += __shfl_down(s2, off, 64);
    }
    if ((j & 63) == 0) { r1[j >> 6] = s1; r2[j >> 6] = s2; }
    __syncthreads();
    if (j == 0) {
        float S1 = r1[0] + r1[1] + r1[2] + r1[3];
        float S2 = r2[0] + r2[1] + r2[2] + r2[3];
        const float inv_n = 1.f / 65536.f;
        float mu  = S1 * inv_n;
        float var = S2 * inv_n - mu * mu;
        float rs  = rsqrtf(var + EPS_F);
        float sc  = bg[c] * rs;
        stats[128 + c] = sc;
        stats[192 + c] = bb[c] - mu * sc;
    }
}

// ---------------- dispatch 4: zlite (blocks 0..2047) U scat (2048..2175) ---
__global__ __launch_bounds__(256)
void k_zs(const float* __restrict__ h_in, const float* __restrict__ stats,
          unsigned short* __restrict__ zb16,
          const int* __restrict__ ei, const float* __restrict__ ew,
          int* __restrict__ cur, int* __restrict__ csrs, float* __restrict__ csrw)
{
    const int j = threadIdx.x;
    if (blockIdx.x >= NB) {               // ---- CSR scatter ----
        int e = (blockIdx.x - NB) * 256 + j;
        unsigned long long bal = __ballot(ei[2 * e + 1] != 0);
        int m = (bal != 0ull) ? 1 : 0;
        int d = edge_dst(ei, m, e);
        int pos = atomicAdd(&cur[d], 1);
        csrs[pos] = edge_src(ei, m, e);
        csrw[pos] = ew[e];
        return;
    }
    // ---- z = leaky(BN(h)) -> bf16 stream ----
    __shared__ float scs[64], shs[64];
    const int b = blockIdx.x;
    if (j < 64)        scs[j] = stats[128 + j];
    else if (j < 128)  shs[j - 64] = stats[192 + (j - 64)];
    __syncthreads();
    const float4* hb = (const float4*)(h_in + (size_t)b * NTC);
    float4 a = hb[2 * j], c4 = hb[2 * j + 1];     // elems 8j..8j+7 (t*64+c order)
    const int c0 = (j * 8) & 63;
    float z0 = a.x  * scs[c0+0] + shs[c0+0];
    float z1 = a.y  * scs[c0+1] + shs[c0+1];
    float z2 = a.z  * scs[c0+2] + shs[c0+2];
    float z3 = a.w  * scs[c0+3] + shs[c0+3];
    float z4 = c4.x * scs[c0+4] + shs[c0+4];
    float z5 = c4.y * scs[c0+5] + shs[c0+5];
    float z6 = c4.z * scs[c0+6] + shs[c0+6];
    float z7 = c4.w * scs[c0+7] + shs[c0+7];
    z0 = (z0 >= 0.f) ? z0 : SLOPE_F * z0;  z1 = (z1 >= 0.f) ? z1 : SLOPE_F * z1;
    z2 = (z2 >= 0.f) ? z2 : SLOPE_F * z2;  z3 = (z3 >= 0.f) ? z3 : SLOPE_F * z3;
    z4 = (z4 >= 0.f) ? z4 : SLOPE_F * z4;  z5 = (z5 >= 0.f) ? z5 : SLOPE_F * z5;
    z6 = (z6 >= 0.f) ? z6 : SLOPE_F * z6;  z7 = (z7 >= 0.f) ? z7 : SLOPE_F * z7;
    uint4 q;
    q.x = pk2(z0, z1); q.y = pk2(z2, z3); q.z = pk2(z4, z5); q.w = pk2(z6, z7);
    ((uint4*)(zb16 + (size_t)b * NTC))[j] = q;
}

// ---------------- hop 1: gather z (bf16) + fused out = h + z@W0 + p1@W1 ----
// 8-deep gather MLP; out written once (no RMW read); p1 stored int16
// (per-node scale, eps <= max|p1|/32767 ~ 1e-3 -- R1-verified numerics).
__global__ __launch_bounds__(256, 4)
void k_hop1(const unsigned short* __restrict__ p_in, const float* __restrict__ h_in,
            const int* __restrict__ rowp, const int* __restrict__ csrs,
            const float* __restrict__ csrw, const unsigned short* __restrict__ twB,
            const float* __restrict__ tb,
            unsigned short* __restrict__ p1q, float* __restrict__ p1scl,
            float* __restrict__ out)
{
    __shared__ __align__(16) unsigned short pA[32 * 64];   // bf16 p1, 4KB
    __shared__ __align__(16) unsigned short zA[32 * 64];   // bf16 z[d], 4KB
    __shared__ float hl[32 * 65];                          // fp32 h residual
    __shared__ float mred[4];
    const int d = blockIdx.x, j = threadIdx.x;

    {   // stage own z row (for z@W0) and h row (residual)
        uint4 zv = ((const uint4*)(p_in + (size_t)d * NTC))[j];
        ((uint4*)zA)[j] = zv;
        const float4* hb4 = (const float4*)(h_in + (size_t)d * NTC);
        float4 h0 = hb4[2 * j], h1 = hb4[2 * j + 1];
        int tt = j >> 3, c0 = (j & 7) * 8;
        float* q = &hl[tt * 65 + c0];
        q[0] = h0.x; q[1] = h0.y; q[2] = h0.z; q[3] = h0.w;
        q[4] = h1.x; q[5] = h1.y; q[6] = h1.z; q[7] = h1.w;
    }

    const int beg = rowp[d], end = rowp[d + 1];
    float acc[8];
#pragma unroll
    for (int r = 0; r < 8; ++r) acc[r] = 0.f;
    int e = beg;
    for (; e + 8 <= end; e += 8) {                // 8 gathers in flight
        int   s0 = csrs[e],   s1 = csrs[e+1], s2 = csrs[e+2], s3 = csrs[e+3];
        int   s4 = csrs[e+4], s5 = csrs[e+5], s6 = csrs[e+6], s7 = csrs[e+7];
        float w0 = csrw[e],   w1 = csrw[e+1], w2 = csrw[e+2], w3 = csrw[e+3];
        float w4 = csrw[e+4], w5 = csrw[e+5], w6 = csrw[e+6], w7 = csrw[e+7];
        uint4 v0 = ((const uint4*)(p_in + (size_t)s0 * NTC))[j];
        uint4 v1 = ((const uint4*)(p_in + (size_t)s1 * NTC))[j];
        uint4 v2 = ((const uint4*)(p_in + (size_t)s2 * NTC))[j];
        uint4 v3 = ((const uint4*)(p_in + (size_t)s3 * NTC))[j];
        uint4 v4 = ((const uint4*)(p_in + (size_t)s4 * NTC))[j];
        uint4 v5 = ((const uint4*)(p_in + (size_t)s5 * NTC))[j];
        uint4 v6 = ((const uint4*)(p_in + (size_t)s6 * NTC))[j];
        uint4 v7 = ((const uint4*)(p_in + (size_t)s7 * NTC))[j];
        accv8(acc, v0, w0); accv8(acc, v1, w1);
        accv8(acc, v2, w2); accv8(acc, v3, w3);
        accv8(acc, v4, w4); accv8(acc, v5, w5);
        accv8(acc, v6, w6); accv8(acc, v7, w7);
    }
    for (; e + 2 <= end; e += 2) {
        int s0 = csrs[e],  s1 = csrs[e+1];
        float w0 = csrw[e], w1 = csrw[e+1];
        uint4 v0 = ((const uint4*)(p_in + (size_t)s0 * NTC))[j];
        uint4 v1 = ((const uint4*)(p_in + (size_t)s1 * NTC))[j];
        accv8(acc, v0, w0); accv8(acc, v1, w1);
    }
    if (e < end) {
        int s0 = csrs[e];
        float w0 = csrw[e];
        uint4 v0 = ((const uint4*)(p_in + (size_t)s0 * NTC))[j];
        accv8(acc, v0, w0);
    }

    // ---- per-node max|p1| reduce (for int16 scale) ----
    const int lane = j & 63, w = j >> 6;
    float m = 0.f;
#pragma unroll
    for (int r = 0; r < 8; ++r) m = fmaxf(m, fabsf(acc[r]));
#pragma unroll
    for (int off = 32; off > 0; off >>= 1)
        m = fmaxf(m, __shfl_down(m, off, 64));
    if (lane == 0) mred[w] = m;
    __syncthreads();
    const float mv = fmaxf(fmaxf(mred[0], mred[1]), fmaxf(mred[2], mred[3]));
    const float inv = (mv > 0.f) ? (32767.f / mv) : 0.f;
    if (j == 0) p1scl[d] = mv * (1.f / 32767.f);

    {   // int16 p1 store: thread j owns elems 8j..8j+7 of [t][c] row-major
        uint4 qv;
        qv.x = pkq2(acc[0], acc[1], inv);
        qv.y = pkq2(acc[2], acc[3], inv);
        qv.z = pkq2(acc[4], acc[5], inv);
        qv.w = pkq2(acc[6], acc[7], inv);
        ((uint4*)(p1q + (size_t)d * NTC))[j] = qv;
    }
    uint4 pv;
    pv.x = pk2(acc[0], acc[1]); pv.y = pk2(acc[2], acc[3]);
    pv.z = pk2(acc[4], acc[5]); pv.w = pk2(acc[6], acc[7]);
    ((uint4*)pA)[j] = pv;                         // pA[t][c], t=j>>3
    __syncthreads();

    const int n16 = lane & 15, quad = lane >> 4;
    const int g = w * 16 + n16;

    // A-frags: z (for W0) and p1 (for W1); B-frags: W0^T, W1^T
    bf16x8 za00 = *(const bf16x8*)(zA + (n16)      * 64 +      quad * 8);
    bf16x8 za01 = *(const bf16x8*)(zA + (n16)      * 64 + 32 + quad * 8);
    bf16x8 za10 = *(const bf16x8*)(zA + (16 + n16) * 64 +      quad * 8);
    bf16x8 za11 = *(const bf16x8*)(zA + (16 + n16) * 64 + 32 + quad * 8);
    bf16x8 pa00 = *(const bf16x8*)(pA + (n16)      * 64 +      quad * 8);
    bf16x8 pa01 = *(const bf16x8*)(pA + (n16)      * 64 + 32 + quad * 8);
    bf16x8 pa10 = *(const bf16x8*)(pA + (16 + n16) * 64 +      quad * 8);
    bf16x8 pa11 = *(const bf16x8*)(pA + (16 + n16) * 64 + 32 + quad * 8);
    bf16x8 b0w0 = *(const bf16x8*)(twB + g * 64 +      quad * 8);
    bf16x8 b1w0 = *(const bf16x8*)(twB + g * 64 + 32 + quad * 8);
    bf16x8 b0w1 = *(const bf16x8*)(twB + 4096 + g * 64 +      quad * 8);
    bf16x8 b1w1 = *(const bf16x8*)(twB + 4096 + g * 64 + 32 + quad * 8);

    f32x4 d0 = {0.f, 0.f, 0.f, 0.f};
    f32x4 d1 = {0.f, 0.f, 0.f, 0.f};
    d0 = __builtin_amdgcn_mfma_f32_16x16x32_bf16(za00, b0w0, d0, 0, 0, 0);
    d0 = __builtin_amdgcn_mfma_f32_16x16x32_bf16(za01, b1w0, d0, 0, 0, 0);
    d0 = __builtin_amdgcn_mfma_f32_16x16x32_bf16(pa00, b0w1, d0, 0, 0, 0);
    d0 = __builtin_amdgcn_mfma_f32_16x16x32_bf16(pa01, b1w1, d0, 0, 0, 0);
    d1 = __builtin_amdgcn_mfma_f32_16x16x32_bf16(za10, b0w0, d1, 0, 0, 0);
    d1 = __builtin_amdgcn_mfma_f32_16x16x32_bf16(za11, b1w0, d1, 0, 0, 0);
    d1 = __builtin_amdgcn_mfma_f32_16x16x32_bf16(pa10, b0w1, d1, 0, 0, 0);
    d1 = __builtin_amdgcn_mfma_f32_16x16x32_bf16(pa11, b1w1, d1, 0, 0, 0);

    const float tbg = tb[g];
    float* ob = out + (size_t)d * NTC + g * 32;   // out[b][g][t], pure store
    {
        float4 v;                                  // mtile 0: t = quad*4..+3
        v.x = d0[0] + tbg + hl[(quad * 4 + 0) * 65 + g];
        v.y = d0[1] + tbg + hl[(quad * 4 + 1) * 65 + g];
        v.z = d0[2] + tbg + hl[(quad * 4 + 2) * 65 + g];
        v.w = d0[3] + tbg + hl[(quad * 4 + 3) * 65 + g];
        *(float4*)(ob + quad * 4) = v;
    }
    {
        float4 v;                                  // mtile 1: t = 16+quad*4..+3
        v.x = d1[0] + tbg + hl[(16 + quad * 4 + 0) * 65 + g];
        v.y = d1[1] + tbg + hl[(16 + quad * 4 + 1) * 65 + g];
        v.z = d1[2] + tbg + hl[(16 + quad * 4 + 2) * 65 + g];
        v.w = d1[3] + tbg + hl[(16 + quad * 4 + 3) * 65 + g];
        *(float4*)(ob + 16 + quad * 4) = v;
    }
}

// ---------------- hop 2: int16 gather (8-deep) + FP32 LDS matmul -----------
// Aggregation and the W2 matmul stay fp32 (the precision-critical path).
__global__ __launch_bounds__(256, 4)
void k_hop2(const unsigned short* __restrict__ p1q, const float* __restrict__ p1scl,
            const int* __restrict__ rowp, const int* __restrict__ csrs,
            const float* __restrict__ csrw, const float* __restrict__ tw,
            float* __restrict__ out)
{
    __shared__ float pl[32 * 65];
    __shared__ __align__(16) float W[64 * 64];
    const int d = blockIdx.x, j = threadIdx.x;
#pragma unroll
    for (int r = 0; r < 16; ++r) { int idx = j + r * 256; W[idx] = tw[idx]; }
    const int beg = rowp[d], end = rowp[d + 1];
    float acc[8];
#pragma unroll
    for (int r = 0; r < 8; ++r) acc[r] = 0.f;
    int e = beg;
    for (; e + 8 <= end; e += 8) {                // 8 gathers in flight (16B each)
        int   s0 = csrs[e],   s1 = csrs[e+1], s2 = csrs[e+2], s3 = csrs[e+3];
        int   s4 = csrs[e+4], s5 = csrs[e+5], s6 = csrs[e+6], s7 = csrs[e+7];
        float w0 = csrw[e]   * p1scl[s0];
        float w1 = csrw[e+1] * p1scl[s1];
        float w2 = csrw[e+2] * p1scl[s2];
        float w3 = csrw[e+3] * p1scl[s3];
        float w4 = csrw[e+4] * p1scl[s4];
        float w5 = csrw[e+5] * p1scl[s5];
        float w6 = csrw[e+6] * p1scl[s6];
        float w7 = csrw[e+7] * p1scl[s7];
        uint4 v0 = ((const uint4*)(p1q + (size_t)s0 * NTC))[j];
        uint4 v1 = ((const uint4*)(p1q + (size_t)s1 * NTC))[j];
        uint4 v2 = ((const uint4*)(p1q + (size_t)s2 * NTC))[j];
        uint4 v3 = ((const uint4*)(p1q + (size_t)s3 * NTC))[j];
        uint4 v4 = ((const uint4*)(p1q + (size_t)s4 * NTC))[j];
        uint4 v5 = ((const uint4*)(p1q + (size_t)s5 * NTC))[j];
        uint4 v6 = ((const uint4*)(p1q + (size_t)s6 * NTC))[j];
        uint4 v7 = ((const uint4*)(p1q + (size_t)s7 * NTC))[j];
        acci16(acc, v0, w0); acci16(acc, v1, w1);
        acci16(acc, v2, w2); acci16(acc, v3, w3);
        acci16(acc, v4, w4); acci16(acc, v5, w5);
        acci16(acc, v6, w6); acci16(acc, v7, w7);
    }
    for (; e + 2 <= end; e += 2) {
        int s0 = csrs[e],  s1 = csrs[e+1];
        float w0 = csrw[e]   * p1scl[s0];
        float w1 = csrw[e+1] * p1scl[s1];
        uint4 v0 = ((const uint4*)(p1q + (size_t)s0 * NTC))[j];
        uint4 v1 = ((const uint4*)(p1q + (size_t)s1 * NTC))[j];
        acci16(acc, v0, w0); acci16(acc, v1, w1);
    }
    if (e < end) {
        int s0 = csrs[e];
        float w0 = csrw[e] * p1scl[s0];
        uint4 v0 = ((const uint4*)(p1q + (size_t)s0 * NTC))[j];
        acci16(acc, v0, w0);
    }
    {
        int tt = j >> 3, c0 = (j & 7) * 8;        // thread owns elems j*8..+7
        float* q = &pl[tt * 65 + c0];
#pragma unroll
        for (int s = 0; s < 8; ++s) q[s] = acc[s];
    }
    __syncthreads();
    const int t = j & 31, gq = (j >> 5) * 8;
    float accm[8];
#pragma unroll
    for (int r = 0; r < 8; ++r) accm[r] = 0.f;
    for (int f = 0; f < 64; ++f) {
        float pv = pl[t * 65 + f];
        const float4* Wr = (const float4*)&W[f * 64 + gq];
        float4 wa = Wr[0], wb = Wr[1];
        accm[0] += pv*wa.x; accm[1] += pv*wa.y; accm[2] += pv*wa.z; accm[3] += pv*wa.w;
        accm[4] += pv*wb.x; accm[5] += pv*wb.y; accm[6] += pv*wb.z; accm[7] += pv*wb.w;
    }
    float* ob = out + (size_t)d * NTC;
#pragma unroll
    for (int r = 0; r < 8; ++r)
        ob[(gq + r) * 32 + t] += accm[r];         // block owns node d: safe RMW
}

// ---------------- launch ----------------
// workspace floats:
//   [0, 4194304)          h_in [b][t][c] fp32
//   [4194304, 6291456)    p1q int16 [b][t][c] (ushort, 8MB)
//   [6291456, 6293504)    p1scl [b] fp32 (8KB)
//   [8388608, 10485760)   z_bf16 [b][t][c] (ushort, 8MB)
//   [10485760, +256)      stats (scale[64]@128, shift[64]@192)
//   [10486016, +6144)     wAb (bf16 conv A-layout, 24KB)
//   [10492160, +6144)     twB (bf16 tag W^T B-layout, 24KB)
//   [10498304, +262144)   partials [b][128]
//   [10760448, ...)       ints: hist(2048) rowp(2049+pad) cur(2048)
//                               csrs(32768) csrw(32768)
extern "C" void kernel_launch(void* const* d_in, const int* in_sizes, int n_in,
                              void* d_out, int out_size, void* d_ws, size_t ws_size,
                              hipStream_t stream)
{
    const float* x  = (const float*)d_in[0];
    const int*   ei = (const int*)  d_in[1];
    const float* ew = (const float*)d_in[2];
    const float* cw = (const float*)d_in[3];
    const float* cb = (const float*)d_in[4];
    const float* lg = (const float*)d_in[5];
    const float* lb = (const float*)d_in[6];
    const float* bg = (const float*)d_in[7];
    const float* bb = (const float*)d_in[8];
    const float* tw = (const float*)d_in[9];
    const float* tb = (const float*)d_in[10];
    float* out = (float*)d_out;
    float* ws  = (float*)d_ws;

    float*          h_in  = ws;
    unsigned short* p1q   = (unsigned short*)(ws + 4194304);
    float*          p1scl = ws + 6291456;
    unsigned short* zbf   = (unsigned short*)(ws + 8388608);
    float*          stats = ws + 10485760;
    unsigned short* wAb   = (unsigned short*)(ws + 10486016);
    unsigned short* twB   = (unsigned short*)(ws + 10492160);
    float*          parts = ws + 10498304;
    int*            ib    = (int*)(ws + 10760448);
    int*   hist  = ib;
    int*   rowp  = ib + 2048;
    int*   cur   = ib + 4100;
    int*   csrs  = ib + 6148;
    float* csrw  = (float*)(ib + 38916);

    k_pre  <<<96,       256, 0, stream>>>(hist, cw, wAb, tw, twB);
    k_main <<<NB + 128, 256, 0, stream>>>(x, wAb, cb, lg, lb, h_in, parts, ei, hist);
    k_mid  <<<65,       256, 0, stream>>>(hist, rowp, cur, parts, bg, bb, stats);
    k_zs   <<<NB + 128, 256, 0, stream>>>(h_in, stats, zbf, ei, ew, cur, csrs, csrw);
    k_hop1 <<<NB,       256, 0, stream>>>(zbf, h_in, rowp, csrs, csrw, twB, tb, p1q, p1scl, out);
    k_hop2 <<<NB,       256, 0, stream>>>(p1q, p1scl, rowp, csrs, csrw, tw + 8192, out);
}

// Round 5
// 163.021 us; speedup vs baseline: 1.1953x; 1.0114x over previous
//
#include <hip/hip_runtime.h>
#include <cstddef>

// B=2048, C_IN=C_OUT=64, T=32, E=32768, K_HOPS=2, KSIZE=3
#define NB   2048
#define NE   32768
#define NTC  2048      // T*C elems per node
#define SLOPE_F 0.01f
#define EPS_F   1e-5f

typedef short bf16x8 __attribute__((ext_vector_type(8)));
typedef float f32x4  __attribute__((ext_vector_type(4)));

// bf16 helpers (manual, RNE pack)
__device__ __forceinline__ unsigned short f2bf(float f) {
    unsigned u = __builtin_bit_cast(unsigned, f);
    u += 0x7FFF + ((u >> 16) & 1);
    return (unsigned short)(u >> 16);
}
__device__ __forceinline__ float bflo(unsigned v) {
    return __builtin_bit_cast(float, v << 16);
}
__device__ __forceinline__ float bfhi(unsigned v) {
    return __builtin_bit_cast(float, v & 0xFFFF0000u);
}
__device__ __forceinline__ unsigned pk2(float lo, float hi) {
    return (unsigned)f2bf(lo) | ((unsigned)f2bf(hi) << 16);
}
// unpack-accumulate 8 bf16 lanes of a uint4 into acc[0..7]
__device__ __forceinline__ void accv8(float* acc, const uint4& v, float wt) {
    acc[0] += wt * bflo(v.x); acc[1] += wt * bfhi(v.x);
    acc[2] += wt * bflo(v.y); acc[3] += wt * bfhi(v.y);
    acc[4] += wt * bflo(v.z); acc[5] += wt * bfhi(v.z);
    acc[6] += wt * bflo(v.w); acc[7] += wt * bfhi(v.w);
}
// unpack-accumulate 8 int16 lanes of a uint4 into acc[0..7] (wt has scale folded)
__device__ __forceinline__ void acci16(float* acc, const uint4& v, float wt) {
    acc[0] += wt * (float)(short)(v.x & 0xFFFFu); acc[1] += wt * (float)(short)(v.x >> 16);
    acc[2] += wt * (float)(short)(v.y & 0xFFFFu); acc[3] += wt * (float)(short)(v.y >> 16);
    acc[4] += wt * (float)(short)(v.z & 0xFFFFu); acc[5] += wt * (float)(short)(v.z >> 16);
    acc[6] += wt * (float)(short)(v.w & 0xFFFFu); acc[7] += wt * (float)(short)(v.w >> 16);
}
__device__ __forceinline__ unsigned pkq2(float a, float b, float inv) {
    int qa = __float2int_rn(a * inv);
    int qb = __float2int_rn(b * inv);
    return ((unsigned)qa & 0xFFFFu) | ((unsigned)qb << 16);
}
// split f into bf16 hi + bf16 lo (lo = exact fp32 residual, then RNE to bf16)
__device__ __forceinline__ void spl2(float a, float b, unsigned& hw, unsigned& lw) {
    unsigned short ha = f2bf(a), hb = f2bf(b);
    float ra = a - bflo((unsigned)ha);
    float rb = b - bflo((unsigned)hb);
    hw = (unsigned)ha | ((unsigned)hb << 16);
    lw = (unsigned)f2bf(ra) | ((unsigned)f2bf(rb) << 16);
}

// ---------------- edge-index width handling (per-wave ballot detect) -------
// int64 layout: high words ei[2e+1] all 0 (ids < 2048). int32 layout:
// P(64 sampled ids all zero) = 2048^-64 ~ 0. Wave-local ballot decides.
__device__ __forceinline__ int edge_src(const int* ei, int m, int e) {
    return m ? ei[e] : ei[2 * e];
}
__device__ __forceinline__ int edge_dst(const int* ei, int m, int e) {
    return m ? ei[NE + e] : ei[2 * (NE + e)];
}

// ---------------- dispatch 1: zero hist + pack weights ---------------------
//   blocks 0..47:   wAb[(kk*64+o)*64+i] = bf16 w[o][i][kk]    (conv A-layout)
//   blocks 48..95:  twB[m][g*64+k]      = bf16 tw[m][k][g]    (tag B-layout, W^T)
//   blocks 96..111: twBlo[g*64+k]       = bf16(W2 - bf16(W2)) (split-lo of W2)
//   first 2048 flat threads: hist = 0   (replaces hipMemsetAsync)
__global__ __launch_bounds__(256)
void k_pre(int* __restrict__ hist, const float* __restrict__ cw,
           unsigned short* __restrict__ wAb, const float* __restrict__ tw,
           unsigned short* __restrict__ twB, unsigned short* __restrict__ twBlo)
{
    int gid = blockIdx.x * 256 + threadIdx.x;
    if (gid < 2048) hist[gid] = 0;
    if (blockIdx.x < 48) {
        int idx = gid;                    // 0..12287
        int kk = idx >> 12, o = (idx >> 6) & 63, i = idx & 63;
        wAb[idx] = f2bf(cw[o * 192 + i * 3 + kk]);
    } else if (blockIdx.x < 96) {
        int idx = gid - 48 * 256;         // 0..12287
        int mm = idx >> 12, rem = idx & 4095;
        int g = rem >> 6, k = rem & 63;
        twB[idx] = f2bf(tw[mm * 4096 + k * 64 + g]);
    } else {                              // blocks 96..111: W2 split-lo
        int idx = gid - 96 * 256;         // 0..4095
        int g = idx >> 6, k = idx & 63;
        float v = tw[2 * 4096 + k * 64 + g];
        unsigned short hi = f2bf(v);
        twBlo[idx] = f2bf(v - bflo((unsigned)hi));
    }
}

// ---------------- dispatch 2: convln (blocks 0..2047) U hist (2048..2175) --
__global__ __launch_bounds__(256, 4)
void k_main(const float* __restrict__ x, const unsigned short* __restrict__ wAb,
            const float* __restrict__ cb, const float* __restrict__ lg,
            const float* __restrict__ lb, float* __restrict__ h_in,
            float* __restrict__ partials,
            const int* __restrict__ ei, int* __restrict__ hist)
{
    if (blockIdx.x >= NB) {               // ---- hist part (whole blocks) ----
        int e = (blockIdx.x - NB) * 256 + threadIdx.x;
        unsigned long long bal = __ballot(ei[2 * e + 1] != 0);
        int m = (bal != 0ull) ? 1 : 0;
        atomicAdd(&hist[edge_dst(ei, m, e)], 1);
        return;
    }
    __shared__ __align__(16) unsigned short xT[36 * 72];
    __shared__ float hT[32 * 65];
    __shared__ float red1[64], red2[64];
    __shared__ float wsum[8];
    __shared__ float bcast[2];

    const int b = blockIdx.x, j = threadIdx.x;
    const float* __restrict__ xg = x + (size_t)b * NTC;

    {   // stage x -> bf16 xT[t+2][i]; zero-pad rows 0,1,34,35
        unsigned* xTd = (unsigned*)xT;
        int t = j & 31, p = j >> 5;
#pragma unroll
        for (int r = 0; r < 4; ++r) {
            int i0 = (r * 8 + p) * 2;
            float v0 = xg[i0 * 32 + t];
            float v1 = xg[(i0 + 1) * 32 + t];
            xTd[(t + 2) * 36 + (i0 >> 1)] = pk2(v0, v1);
        }
        if (j < 72)       xTd[j] = 0u;
        else if (j < 144) xTd[1224 + (j - 72)] = 0u;   // rows 34,35
    }
    __syncthreads();

    const int lane = j & 63, w = j >> 6;
    const int n16 = lane & 15, quad = lane >> 4;

    bf16x8 afr[3][2];
#pragma unroll
    for (int kk = 0; kk < 3; ++kk)
#pragma unroll
        for (int s = 0; s < 2; ++s) {
            int off16 = (kk * 64 + w * 16 + n16) * 64 + s * 32 + quad * 8;
            afr[kk][s] = *(const bf16x8*)(wAb + off16);
        }

    f32x4 acc0 = {0.f, 0.f, 0.f, 0.f};
    f32x4 acc1 = {0.f, 0.f, 0.f, 0.f};
#pragma unroll
    for (int kk = 0; kk < 3; ++kk)
#pragma unroll
        for (int s = 0; s < 2; ++s) {
            bf16x8 b0 = *(const bf16x8*)(xT + (n16 + kk) * 72 + s * 32 + quad * 8);
            bf16x8 b1 = *(const bf16x8*)(xT + (16 + n16 + kk) * 72 + s * 32 + quad * 8);
            acc0 = __builtin_amdgcn_mfma_f32_16x16x32_bf16(afr[kk][s], b0, acc0, 0, 0, 0);
            acc1 = __builtin_amdgcn_mfma_f32_16x16x32_bf16(afr[kk][s], b1, acc1, 0, 0, 0);
        }

    float vals[2][4];
    float s1 = 0.f, s2 = 0.f;
#pragma unroll
    for (int r = 0; r < 4; ++r) {
        float cbv = cb[w * 16 + quad * 4 + r];
        float v0 = acc0[r] + cbv;
        float v1 = acc1[r] + cbv;
        v0 = (v0 >= 0.f) ? v0 : SLOPE_F * v0;
        v1 = (v1 >= 0.f) ? v1 : SLOPE_F * v1;
        vals[0][r] = v0; vals[1][r] = v1;
        s1 += v0 + v1; s2 += v0 * v0 + v1 * v1;
    }
#pragma unroll
    for (int off = 32; off > 0; off >>= 1) {
        s1 += __shfl_down(s1, off, 64);
        s2 += __shfl_down(s2, off, 64);
    }
    if (lane == 0) { wsum[w] = s1; wsum[4 + w] = s2; }
    __syncthreads();
    if (j == 0) {
        float S1 = wsum[0] + wsum[1] + wsum[2] + wsum[3];
        float S2 = wsum[4] + wsum[5] + wsum[6] + wsum[7];
        float mu  = S1 * (1.f / 2048.f);
        float var = S2 * (1.f / 2048.f) - mu * mu;
        bcast[0] = mu;
        bcast[1] = rsqrtf(var + EPS_F);
    }
    __syncthreads();
    const float mu = bcast[0], rs = bcast[1];
    float po1[4] = {0.f, 0.f, 0.f, 0.f}, po2[4] = {0.f, 0.f, 0.f, 0.f};
#pragma unroll
    for (int nt = 0; nt < 2; ++nt) {
        int t = nt * 16 + n16;
#pragma unroll
        for (int r = 0; r < 4; ++r) {
            int o = w * 16 + quad * 4 + r;
            float h = (vals[nt][r] - mu) * rs * lg[o * 32 + t] + lb[o * 32 + t];
            hT[t * 65 + o] = h;
            po1[r] += h; po2[r] += h * h;
        }
    }
#pragma unroll
    for (int off = 8; off > 0; off >>= 1) {
#pragma unroll
        for (int r = 0; r < 4; ++r) {
            po1[r] += __shfl_down(po1[r], off, 16);
            po2[r] += __shfl_down(po2[r], off, 16);
        }
    }
    if (n16 == 0) {
#pragma unroll
        for (int r = 0; r < 4; ++r) {
            int o = w * 16 + quad * 4 + r;
            red1[o] = po1[r];
            red2[o] = po2[r];
        }
    }
    __syncthreads();
    float* hb = h_in + (size_t)b * NTC;
#pragma unroll
    for (int r = 0; r < 8; ++r) {                  // coalesced h_in store
        int idx = j + r * 256;
        hb[idx] = hT[(idx >> 6) * 65 + (idx & 63)];
    }
    float* pb_ = partials + (size_t)b * 128;       // coalesced 512B store
    if (j < 64)       pb_[j] = red1[j];
    else if (j < 128) pb_[j] = red2[j - 64];
}

// ---------------- dispatch 3: scan (block 0) U bnred (blocks 1..64) --------
__global__ __launch_bounds__(256)
void k_mid(const int* __restrict__ hist, int* __restrict__ rowp,
           int* __restrict__ cur, const float* __restrict__ partials,
           const float* __restrict__ bg, const float* __restrict__ bb,
           float* __restrict__ stats)
{
    __shared__ int part[256];
    __shared__ float r1[4], r2[4];
    const int j = threadIdx.x;
    if (blockIdx.x == 0) {                // ---- CSR row-pointer scan ----
        int loc[8]; int s = 0;
#pragma unroll
        for (int r = 0; r < 8; ++r) { loc[r] = hist[j * 8 + r]; s += loc[r]; }
        part[j] = s;
        __syncthreads();
        for (int off = 1; off < 256; off <<= 1) {
            int v = (j >= off) ? part[j - off] : 0;
            __syncthreads();
            part[j] += v;
            __syncthreads();
        }
        int excl = part[j] - s;
#pragma unroll
        for (int r = 0; r < 8; ++r) {
            rowp[j * 8 + r] = excl;
            cur [j * 8 + r] = excl;
            excl += loc[r];
        }
        if (j == 255) rowp[2048] = excl;  // == NE
        return;
    }
    // ---- BN partial reduce, c = blockIdx.x - 1 ----
    const int c = blockIdx.x - 1;
    float s1 = 0.f, s2 = 0.f;
    for (int b = j; b < NB; b += 256) {
        const float* p = partials + (size_t)b * 128;
        s1 += p[c];
        s2 += p[64 + c];
    }
#pragma unroll
    for (int off = 32; off > 0; off >>= 1) {
        s1 += __shfl_down(s1, off, 64);
        s2 += __shfl_down(s2, off, 64);
    }
    if ((j & 63) == 0) { r1[j >> 6] = s1; r2[j >> 6] = s2; }
    __syncthreads();
    if (j == 0) {
        float S1 = r1[0] + r1[1] + r1[2] + r1[3];
        float S2 = r2[0] + r2[1] + r2[2] + r2[3];
        const float inv_n = 1.f / 65536.f;
        float mu  = S1 * inv_n;
        float var = S2 * inv_n - mu * mu;
        float rs  = rsqrtf(var + EPS_F);
        float sc  = bg[c] * rs;
        stats[128 + c] = sc;
        stats[192 + c] = bb[c] - mu * sc;
    }
}

// ---------------- dispatch 4: zlite (blocks 0..2047) U scat (2048..2175) ---
__global__ __launch_bounds__(256)
void k_zs(const float* __restrict__ h_in, const float* __restrict__ stats,
          unsigned short* __restrict__ zb16,
          const int* __restrict__ ei, const float* __restrict__ ew,
          int* __restrict__ cur, int* __restrict__ csrs, float* __restrict__ csrw)
{
    const int j = threadIdx.x;
    if (blockIdx.x >= NB) {               // ---- CSR scatter ----
        int e = (blockIdx.x - NB) * 256 + j;
        unsigned long long bal = __ballot(ei[2 * e + 1] != 0);
        int m = (bal != 0ull) ? 1 : 0;
        int d = edge_dst(ei, m, e);
        int pos = atomicAdd(&cur[d], 1);
        csrs[pos] = edge_src(ei, m, e);
        csrw[pos] = ew[e];
        return;
    }
    // ---- z = leaky(BN(h)) -> bf16 stream ----
    __shared__ float scs[64], shs[64];
    const int b = blockIdx.x;
    if (j < 64)        scs[j] = stats[128 + j];
    else if (j < 128)  shs[j - 64] = stats[192 + (j - 64)];
    __syncthreads();
    const float4* hb = (const float4*)(h_in + (size_t)b * NTC);
    float4 a = hb[2 * j], c4 = hb[2 * j + 1];     // elems 8j..8j+7 (t*64+c order)
    const int c0 = (j * 8) & 63;
    float z0 = a.x  * scs[c0+0] + shs[c0+0];
    float z1 = a.y  * scs[c0+1] + shs[c0+1];
    float z2 = a.z  * scs[c0+2] + shs[c0+2];
    float z3 = a.w  * scs[c0+3] + shs[c0+3];
    float z4 = c4.x * scs[c0+4] + shs[c0+4];
    float z5 = c4.y * scs[c0+5] + shs[c0+5];
    float z6 = c4.z * scs[c0+6] + shs[c0+6];
    float z7 = c4.w * scs[c0+7] + shs[c0+7];
    z0 = (z0 >= 0.f) ? z0 : SLOPE_F * z0;  z1 = (z1 >= 0.f) ? z1 : SLOPE_F * z1;
    z2 = (z2 >= 0.f) ? z2 : SLOPE_F * z2;  z3 = (z3 >= 0.f) ? z3 : SLOPE_F * z3;
    z4 = (z4 >= 0.f) ? z4 : SLOPE_F * z4;  z5 = (z5 >= 0.f) ? z5 : SLOPE_F * z5;
    z6 = (z6 >= 0.f) ? z6 : SLOPE_F * z6;  z7 = (z7 >= 0.f) ? z7 : SLOPE_F * z7;
    uint4 q;
    q.x = pk2(z0, z1); q.y = pk2(z2, z3); q.z = pk2(z4, z5); q.w = pk2(z6, z7);
    ((uint4*)(zb16 + (size_t)b * NTC))[j] = q;
}

// ---------------- hop 1: gather z (bf16) + fused out = h + z@W0 + p1@W1 ----
__global__ __launch_bounds__(256, 4)
void k_hop1(const unsigned short* __restrict__ p_in, const float* __restrict__ h_in,
            const int* __restrict__ rowp, const int* __restrict__ csrs,
            const float* __restrict__ csrw, const unsigned short* __restrict__ twB,
            const float* __restrict__ tb,
            unsigned short* __restrict__ p1q, float* __restrict__ p1scl,
            float* __restrict__ out)
{
    __shared__ __align__(16) unsigned short pA[32 * 64];   // bf16 p1, 4KB
    __shared__ __align__(16) unsigned short zA[32 * 64];   // bf16 z[d], 4KB
    __shared__ float hl[32 * 65];                          // fp32 h residual
    __shared__ float mred[4];
    const int d = blockIdx.x, j = threadIdx.x;

    {   // stage own z row (for z@W0) and h row (residual)
        uint4 zv = ((const uint4*)(p_in + (size_t)d * NTC))[j];
        ((uint4*)zA)[j] = zv;
        const float4* hb4 = (const float4*)(h_in + (size_t)d * NTC);
        float4 h0 = hb4[2 * j], h1 = hb4[2 * j + 1];
        int tt = j >> 3, c0 = (j & 7) * 8;
        float* q = &hl[tt * 65 + c0];
        q[0] = h0.x; q[1] = h0.y; q[2] = h0.z; q[3] = h0.w;
        q[4] = h1.x; q[5] = h1.y; q[6] = h1.z; q[7] = h1.w;
    }

    const int beg = rowp[d], end = rowp[d + 1];
    float acc[8];
#pragma unroll
    for (int r = 0; r < 8; ++r) acc[r] = 0.f;
    int e = beg;
    for (; e + 8 <= end; e += 8) {                // 8 gathers in flight
        int   s0 = csrs[e],   s1 = csrs[e+1], s2 = csrs[e+2], s3 = csrs[e+3];
        int   s4 = csrs[e+4], s5 = csrs[e+5], s6 = csrs[e+6], s7 = csrs[e+7];
        float w0 = csrw[e],   w1 = csrw[e+1], w2 = csrw[e+2], w3 = csrw[e+3];
        float w4 = csrw[e+4], w5 = csrw[e+5], w6 = csrw[e+6], w7 = csrw[e+7];
        uint4 v0 = ((const uint4*)(p_in + (size_t)s0 * NTC))[j];
        uint4 v1 = ((const uint4*)(p_in + (size_t)s1 * NTC))[j];
        uint4 v2 = ((const uint4*)(p_in + (size_t)s2 * NTC))[j];
        uint4 v3 = ((const uint4*)(p_in + (size_t)s3 * NTC))[j];
        uint4 v4 = ((const uint4*)(p_in + (size_t)s4 * NTC))[j];
        uint4 v5 = ((const uint4*)(p_in + (size_t)s5 * NTC))[j];
        uint4 v6 = ((const uint4*)(p_in + (size_t)s6 * NTC))[j];
        uint4 v7 = ((const uint4*)(p_in + (size_t)s7 * NTC))[j];
        accv8(acc, v0, w0); accv8(acc, v1, w1);
        accv8(acc, v2, w2); accv8(acc, v3, w3);
        accv8(acc, v4, w4); accv8(acc, v5, w5);
        accv8(acc, v6, w6); accv8(acc, v7, w7);
    }
    for (; e + 2 <= end; e += 2) {
        int s0 = csrs[e],  s1 = csrs[e+1];
        float w0 = csrw[e], w1 = csrw[e+1];
        uint4 v0 = ((const uint4*)(p_in + (size_t)s0 * NTC))[j];
        uint4 v1 = ((const uint4*)(p_in + (size_t)s1 * NTC))[j];
        accv8(acc, v0, w0); accv8(acc, v1, w1);
    }
    if (e < end) {
        int s0 = csrs[e];
        float w0 = csrw[e];
        uint4 v0 = ((const uint4*)(p_in + (size_t)s0 * NTC))[j];
        accv8(acc, v0, w0);
    }

    // ---- per-node max|p1| reduce (for int16 scale) ----
    const int lane = j & 63, w = j >> 6;
    float m = 0.f;
#pragma unroll
    for (int r = 0; r < 8; ++r) m = fmaxf(m, fabsf(acc[r]));
#pragma unroll
    for (int off = 32; off > 0; off >>= 1)
        m = fmaxf(m, __shfl_down(m, off, 64));
    if (lane == 0) mred[w] = m;
    __syncthreads();
    const float mv = fmaxf(fmaxf(mred[0], mred[1]), fmaxf(mred[2], mred[3]));
    const float inv = (mv > 0.f) ? (32767.f / mv) : 0.f;
    if (j == 0) p1scl[d] = mv * (1.f / 32767.f);

    {   // int16 p1 store: thread j owns elems 8j..8j+7 of [t][c] row-major
        uint4 qv;
        qv.x = pkq2(acc[0], acc[1], inv);
        qv.y = pkq2(acc[2], acc[3], inv);
        qv.z = pkq2(acc[4], acc[5], inv);
        qv.w = pkq2(acc[6], acc[7], inv);
        ((uint4*)(p1q + (size_t)d * NTC))[j] = qv;
    }
    uint4 pv;
    pv.x = pk2(acc[0], acc[1]); pv.y = pk2(acc[2], acc[3]);
    pv.z = pk2(acc[4], acc[5]); pv.w = pk2(acc[6], acc[7]);
    ((uint4*)pA)[j] = pv;                         // pA[t][c], t=j>>3
    __syncthreads();

    const int n16 = lane & 15, quad = lane >> 4;
    const int g = w * 16 + n16;

    // A-frags: z (for W0) and p1 (for W1); B-frags: W0^T, W1^T
    bf16x8 za00 = *(const bf16x8*)(zA + (n16)      * 64 +      quad * 8);
    bf16x8 za01 = *(const bf16x8*)(zA + (n16)      * 64 + 32 + quad * 8);
    bf16x8 za10 = *(const bf16x8*)(zA + (16 + n16) * 64 +      quad * 8);
    bf16x8 za11 = *(const bf16x8*)(zA + (16 + n16) * 64 + 32 + quad * 8);
    bf16x8 pa00 = *(const bf16x8*)(pA + (n16)      * 64 +      quad * 8);
    bf16x8 pa01 = *(const bf16x8*)(pA + (n16)      * 64 + 32 + quad * 8);
    bf16x8 pa10 = *(const bf16x8*)(pA + (16 + n16) * 64 +      quad * 8);
    bf16x8 pa11 = *(const bf16x8*)(pA + (16 + n16) * 64 + 32 + quad * 8);
    bf16x8 b0w0 = *(const bf16x8*)(twB + g * 64 +      quad * 8);
    bf16x8 b1w0 = *(const bf16x8*)(twB + g * 64 + 32 + quad * 8);
    bf16x8 b0w1 = *(const bf16x8*)(twB + 4096 + g * 64 +      quad * 8);
    bf16x8 b1w1 = *(const bf16x8*)(twB + 4096 + g * 64 + 32 + quad * 8);

    f32x4 d0 = {0.f, 0.f, 0.f, 0.f};
    f32x4 d1 = {0.f, 0.f, 0.f, 0.f};
    d0 = __builtin_amdgcn_mfma_f32_16x16x32_bf16(za00, b0w0, d0, 0, 0, 0);
    d0 = __builtin_amdgcn_mfma_f32_16x16x32_bf16(za01, b1w0, d0, 0, 0, 0);
    d0 = __builtin_amdgcn_mfma_f32_16x16x32_bf16(pa00, b0w1, d0, 0, 0, 0);
    d0 = __builtin_amdgcn_mfma_f32_16x16x32_bf16(pa01, b1w1, d0, 0, 0, 0);
    d1 = __builtin_amdgcn_mfma_f32_16x16x32_bf16(za10, b0w0, d1, 0, 0, 0);
    d1 = __builtin_amdgcn_mfma_f32_16x16x32_bf16(za11, b1w0, d1, 0, 0, 0);
    d1 = __builtin_amdgcn_mfma_f32_16x16x32_bf16(pa10, b0w1, d1, 0, 0, 0);
    d1 = __builtin_amdgcn_mfma_f32_16x16x32_bf16(pa11, b1w1, d1, 0, 0, 0);

    const float tbg = tb[g];
    float* ob = out + (size_t)d * NTC + g * 32;   // out[b][g][t], pure store
    {
        float4 v;                                  // mtile 0: t = quad*4..+3
        v.x = d0[0] + tbg + hl[(quad * 4 + 0) * 65 + g];
        v.y = d0[1] + tbg + hl[(quad * 4 + 1) * 65 + g];
        v.z = d0[2] + tbg + hl[(quad * 4 + 2) * 65 + g];
        v.w = d0[3] + tbg + hl[(quad * 4 + 3) * 65 + g];
        *(float4*)(ob + quad * 4) = v;
    }
    {
        float4 v;                                  // mtile 1: t = 16+quad*4..+3
        v.x = d1[0] + tbg + hl[(16 + quad * 4 + 0) * 65 + g];
        v.y = d1[1] + tbg + hl[(16 + quad * 4 + 1) * 65 + g];
        v.z = d1[2] + tbg + hl[(16 + quad * 4 + 2) * 65 + g];
        v.w = d1[3] + tbg + hl[(16 + quad * 4 + 3) * 65 + g];
        *(float4*)(ob + 16 + quad * 4) = v;
    }
}

// ---------------- hop 2: int16 gather + split-bf16 MFMA matmul -------------
// p2 = pH + pL (exact fp32 residual split); W2 = WH + WL (packed in k_pre).
// out += pH@WH + pH@WL + pL@WH; dropped pL@WL <= |p2||W2|*2^-18 (~0.01 abs).
// Replaces the 1024-FMA/thread fp32 LDS matmul (~27 us VALU-pipe) with 12 MFMA.
__global__ __launch_bounds__(256, 4)
void k_hop2(const unsigned short* __restrict__ p1q, const float* __restrict__ p1scl,
            const int* __restrict__ rowp, const int* __restrict__ csrs,
            const float* __restrict__ csrw,
            const unsigned short* __restrict__ twB2,   // W2 hi, B-layout
            const unsigned short* __restrict__ twB2lo, // W2 lo, B-layout
            float* __restrict__ out)
{
    __shared__ __align__(16) unsigned short pH[32 * 64];   // bf16 p2 hi, 4KB
    __shared__ __align__(16) unsigned short pL[32 * 64];   // bf16 p2 lo, 4KB
    const int d = blockIdx.x, j = threadIdx.x;
    const int beg = rowp[d], end = rowp[d + 1];
    float acc[8];
#pragma unroll
    for (int r = 0; r < 8; ++r) acc[r] = 0.f;
    int e = beg;
    for (; e + 8 <= end; e += 8) {                // 8 gathers in flight (16B each)
        int   s0 = csrs[e],   s1 = csrs[e+1], s2 = csrs[e+2], s3 = csrs[e+3];
        int   s4 = csrs[e+4], s5 = csrs[e+5], s6 = csrs[e+6], s7 = csrs[e+7];
        float w0 = csrw[e]   * p1scl[s0];
        float w1 = csrw[e+1] * p1scl[s1];
        float w2 = csrw[e+2] * p1scl[s2];
        float w3 = csrw[e+3] * p1scl[s3];
        float w4 = csrw[e+4] * p1scl[s4];
        float w5 = csrw[e+5] * p1scl[s5];
        float w6 = csrw[e+6] * p1scl[s6];
        float w7 = csrw[e+7] * p1scl[s7];
        uint4 v0 = ((const uint4*)(p1q + (size_t)s0 * NTC))[j];
        uint4 v1 = ((const uint4*)(p1q + (size_t)s1 * NTC))[j];
        uint4 v2 = ((const uint4*)(p1q + (size_t)s2 * NTC))[j];
        uint4 v3 = ((const uint4*)(p1q + (size_t)s3 * NTC))[j];
        uint4 v4 = ((const uint4*)(p1q + (size_t)s4 * NTC))[j];
        uint4 v5 = ((const uint4*)(p1q + (size_t)s5 * NTC))[j];
        uint4 v6 = ((const uint4*)(p1q + (size_t)s6 * NTC))[j];
        uint4 v7 = ((const uint4*)(p1q + (size_t)s7 * NTC))[j];
        acci16(acc, v0, w0); acci16(acc, v1, w1);
        acci16(acc, v2, w2); acci16(acc, v3, w3);
        acci16(acc, v4, w4); acci16(acc, v5, w5);
        acci16(acc, v6, w6); acci16(acc, v7, w7);
    }
    for (; e + 2 <= end; e += 2) {
        int s0 = csrs[e],  s1 = csrs[e+1];
        float w0 = csrw[e]   * p1scl[s0];
        float w1 = csrw[e+1] * p1scl[s1];
        uint4 v0 = ((const uint4*)(p1q + (size_t)s0 * NTC))[j];
        uint4 v1 = ((const uint4*)(p1q + (size_t)s1 * NTC))[j];
        acci16(acc, v0, w0); acci16(acc, v1, w1);
    }
    if (e < end) {
        int s0 = csrs[e];
        float w0 = csrw[e] * p1scl[s0];
        uint4 v0 = ((const uint4*)(p1q + (size_t)s0 * NTC))[j];
        acci16(acc, v0, w0);
    }
    {   // hi/lo split-pack into LDS tiles (thread j owns elems 8j..8j+7, [t][c])
        uint4 qh, ql;
        spl2(acc[0], acc[1], qh.x, ql.x);
        spl2(acc[2], acc[3], qh.y, ql.y);
        spl2(acc[4], acc[5], qh.z, ql.z);
        spl2(acc[6], acc[7], qh.w, ql.w);
        ((uint4*)pH)[j] = qh;
        ((uint4*)pL)[j] = ql;
    }
    __syncthreads();

    const int lane = j & 63, w = j >> 6;
    const int n16 = lane & 15, quad = lane >> 4;
    const int g = w * 16 + n16;

    bf16x8 ah00 = *(const bf16x8*)(pH + (n16)      * 64 +      quad * 8);
    bf16x8 ah01 = *(const bf16x8*)(pH + (n16)      * 64 + 32 + quad * 8);
    bf16x8 ah10 = *(const bf16x8*)(pH + (16 + n16) * 64 +      quad * 8);
    bf16x8 ah11 = *(const bf16x8*)(pH + (16 + n16) * 64 + 32 + quad * 8);
    bf16x8 al00 = *(const bf16x8*)(pL + (n16)      * 64 +      quad * 8);
    bf16x8 al01 = *(const bf16x8*)(pL + (n16)      * 64 + 32 + quad * 8);
    bf16x8 al10 = *(const bf16x8*)(pL + (16 + n16) * 64 +      quad * 8);
    bf16x8 al11 = *(const bf16x8*)(pL + (16 + n16) * 64 + 32 + quad * 8);
    bf16x8 b0h  = *(const bf16x8*)(twB2   + g * 64 +      quad * 8);
    bf16x8 b1h  = *(const bf16x8*)(twB2   + g * 64 + 32 + quad * 8);
    bf16x8 b0l  = *(const bf16x8*)(twB2lo + g * 64 +      quad * 8);
    bf16x8 b1l  = *(const bf16x8*)(twB2lo + g * 64 + 32 + quad * 8);

    f32x4 d0 = {0.f, 0.f, 0.f, 0.f};
    f32x4 d1 = {0.f, 0.f, 0.f, 0.f};
    // hi @ hi
    d0 = __builtin_amdgcn_mfma_f32_16x16x32_bf16(ah00, b0h, d0, 0, 0, 0);
    d0 = __builtin_amdgcn_mfma_f32_16x16x32_bf16(ah01, b1h, d0, 0, 0, 0);
    d1 = __builtin_amdgcn_mfma_f32_16x16x32_bf16(ah10, b0h, d1, 0, 0, 0);
    d1 = __builtin_amdgcn_mfma_f32_16x16x32_bf16(ah11, b1h, d1, 0, 0, 0);
    // hi @ lo
    d0 = __builtin_amdgcn_mfma_f32_16x16x32_bf16(ah00, b0l, d0, 0, 0, 0);
    d0 = __builtin_amdgcn_mfma_f32_16x16x32_bf16(ah01, b1l, d0, 0, 0, 0);
    d1 = __builtin_amdgcn_mfma_f32_16x16x32_bf16(ah10, b0l, d1, 0, 0, 0);
    d1 = __builtin_amdgcn_mfma_f32_16x16x32_bf16(ah11, b1l, d1, 0, 0, 0);
    // lo @ hi
    d0 = __builtin_amdgcn_mfma_f32_16x16x32_bf16(al00, b0h, d0, 0, 0, 0);
    d0 = __builtin_amdgcn_mfma_f32_16x16x32_bf16(al01, b1h, d0, 0, 0, 0);
    d1 = __builtin_amdgcn_mfma_f32_16x16x32_bf16(al10, b0h, d1, 0, 0, 0);
    d1 = __builtin_amdgcn_mfma_f32_16x16x32_bf16(al11, b1h, d1, 0, 0, 0);

    float* ob = out + (size_t)d * NTC + g * 32;   // out[b][g][t], block owns d
    {
        float4 v = *(float4*)(ob + quad * 4);
        v.x += d0[0]; v.y += d0[1]; v.z += d0[2]; v.w += d0[3];
        *(float4*)(ob + quad * 4) = v;
    }
    {
        float4 v = *(float4*)(ob + 16 + quad * 4);
        v.x += d1[0]; v.y += d1[1]; v.z += d1[2]; v.w += d1[3];
        *(float4*)(ob + 16 + quad * 4) = v;
    }
}

// ---------------- launch ----------------
// workspace floats:
//   [0, 4194304)          h_in [b][t][c] fp32
//   [4194304, 6291456)    p1q int16 [b][t][c] (ushort, 8MB)
//   [6291456, 6293504)    p1scl [b] fp32 (8KB)
//   [8388608, 10485760)   z_bf16 [b][t][c] (ushort, 8MB)
//   [10485760, +256)      stats (scale[64]@128, shift[64]@192)
//   [10486016, +6144)     wAb (bf16 conv A-layout, 24KB)
//   [10492160, +6144)     twB (bf16 tag W^T B-layout, 24KB; m=2 slot = W2 hi)
//   [10498304, +262144)   partials [b][128]
//   [10760448, ...)       ints: hist(2048) rowp(2049+pad) cur(2048)
//                               csrs(32768) csrw(32768)
//   [10832640, +2048)     twBlo (bf16 W2 split-lo B-layout, 8KB)
extern "C" void kernel_launch(void* const* d_in, const int* in_sizes, int n_in,
                              void* d_out, int out_size, void* d_ws, size_t ws_size,
                              hipStream_t stream)
{
    const float* x  = (const float*)d_in[0];
    const int*   ei = (const int*)  d_in[1];
    const float* ew = (const float*)d_in[2];
    const float* cw = (const float*)d_in[3];
    const float* cb = (const float*)d_in[4];
    const float* lg = (const float*)d_in[5];
    const float* lb = (const float*)d_in[6];
    const float* bg = (const float*)d_in[7];
    const float* bb = (const float*)d_in[8];
    const float* tw = (const float*)d_in[9];
    const float* tb = (const float*)d_in[10];
    float* out = (float*)d_out;
    float* ws  = (float*)d_ws;

    float*          h_in  = ws;
    unsigned short* p1q   = (unsigned short*)(ws + 4194304);
    float*          p1scl = ws + 6291456;
    unsigned short* zbf   = (unsigned short*)(ws + 8388608);
    float*          stats = ws + 10485760;
    unsigned short* wAb   = (unsigned short*)(ws + 10486016);
    unsigned short* twB   = (unsigned short*)(ws + 10492160);
    float*          parts = ws + 10498304;
    int*            ib    = (int*)(ws + 10760448);
    unsigned short* twBlo = (unsigned short*)(ws + 10832640);
    int*   hist  = ib;
    int*   rowp  = ib + 2048;
    int*   cur   = ib + 4100;
    int*   csrs  = ib + 6148;
    float* csrw  = (float*)(ib + 38916);

    k_pre  <<<112,      256, 0, stream>>>(hist, cw, wAb, tw, twB, twBlo);
    k_main <<<NB + 128, 256, 0, stream>>>(x, wAb, cb, lg, lb, h_in, parts, ei, hist);
    k_mid  <<<65,       256, 0, stream>>>(hist, rowp, cur, parts, bg, bb, stats);
    k_zs   <<<NB + 128, 256, 0, stream>>>(h_in, stats, zbf, ei, ew, cur, csrs, csrw);
    k_hop1 <<<NB,       256, 0, stream>>>(zbf, h_in, rowp, csrs, csrw, twB, tb, p1q, p1scl, out);
    k_hop2 <<<NB,       256, 0, stream>>>(p1q, p1scl, rowp, csrs, csrw, twB + 8192, twBlo, out);
}

// Round 6
// 159.670 us; speedup vs baseline: 1.2203x; 1.0210x over previous
//
#include <hip/hip_runtime.h>
#include <cstddef>

// B=2048, C_IN=C_OUT=64, T=32, E=32768, K_HOPS=2, KSIZE=3
#define NB   2048
#define NE   32768
#define NTC  2048      // T*C elems per node
#define SLOPE_F 0.01f
#define EPS_F   1e-5f

typedef short bf16x8 __attribute__((ext_vector_type(8)));
typedef float f32x4  __attribute__((ext_vector_type(4)));

// bf16 helpers (manual, RNE pack)
__device__ __forceinline__ unsigned short f2bf(float f) {
    unsigned u = __builtin_bit_cast(unsigned, f);
    u += 0x7FFF + ((u >> 16) & 1);
    return (unsigned short)(u >> 16);
}
__device__ __forceinline__ float bflo(unsigned v) {
    return __builtin_bit_cast(float, v << 16);
}
__device__ __forceinline__ float bfhi(unsigned v) {
    return __builtin_bit_cast(float, v & 0xFFFF0000u);
}
__device__ __forceinline__ unsigned pk2(float lo, float hi) {
    return (unsigned)f2bf(lo) | ((unsigned)f2bf(hi) << 16);
}
// unpack-accumulate 8 bf16 lanes of a uint4 into acc[0..7]
__device__ __forceinline__ void accv8(float* acc, const uint4& v, float wt) {
    acc[0] += wt * bflo(v.x); acc[1] += wt * bfhi(v.x);
    acc[2] += wt * bflo(v.y); acc[3] += wt * bfhi(v.y);
    acc[4] += wt * bflo(v.z); acc[5] += wt * bfhi(v.z);
    acc[6] += wt * bflo(v.w); acc[7] += wt * bfhi(v.w);
}
// unpack-accumulate 8 int16 lanes of a uint4 into acc[0..7] (wt has scale folded)
__device__ __forceinline__ void acci16(float* acc, const uint4& v, float wt) {
    acc[0] += wt * (float)(short)(v.x & 0xFFFFu); acc[1] += wt * (float)(short)(v.x >> 16);
    acc[2] += wt * (float)(short)(v.y & 0xFFFFu); acc[3] += wt * (float)(short)(v.y >> 16);
    acc[4] += wt * (float)(short)(v.z & 0xFFFFu); acc[5] += wt * (float)(short)(v.z >> 16);
    acc[6] += wt * (float)(short)(v.w & 0xFFFFu); acc[7] += wt * (float)(short)(v.w >> 16);
}
__device__ __forceinline__ unsigned pkq2(float a, float b, float inv) {
    int qa = __float2int_rn(a * inv);
    int qb = __float2int_rn(b * inv);
    return ((unsigned)qa & 0xFFFFu) | ((unsigned)qb << 16);
}
// split f into bf16 hi + bf16 lo (lo = exact fp32 residual, then RNE to bf16)
__device__ __forceinline__ void spl2(float a, float b, unsigned& hw, unsigned& lw) {
    unsigned short ha = f2bf(a), hb = f2bf(b);
    float ra = a - bflo((unsigned)ha);
    float rb = b - bflo((unsigned)hb);
    hw = (unsigned)ha | ((unsigned)hb << 16);
    lw = (unsigned)f2bf(ra) | ((unsigned)f2bf(rb) << 16);
}

// ---------------- edge-index width handling (per-wave ballot detect) -------
// int64 layout: high words ei[2e+1] all 0 (ids < 2048). int32 layout:
// P(64 sampled ids all zero) = 2048^-64 ~ 0. Wave-local ballot decides.
__device__ __forceinline__ int edge_src(const int* ei, int m, int e) {
    return m ? ei[e] : ei[2 * e];
}
__device__ __forceinline__ int edge_dst(const int* ei, int m, int e) {
    return m ? ei[NE + e] : ei[2 * (NE + e)];
}

// ---------------- dispatch 1: zero hist + pack weights ---------------------
//   blocks 0..47:   wAb[(kk*64+o)*64+i] = bf16 w[o][i][kk]    (conv A-layout)
//   blocks 48..95:  twB[m][g*64+k]      = bf16 tw[m][k][g]    (tag B-layout, W^T)
//   blocks 96..111: twBlo[g*64+k]       = bf16(W2 - bf16(W2)) (split-lo of W2)
//   first 2048 flat threads: hist = 0   (replaces hipMemsetAsync)
__global__ __launch_bounds__(256)
void k_pre(int* __restrict__ hist, const float* __restrict__ cw,
           unsigned short* __restrict__ wAb, const float* __restrict__ tw,
           unsigned short* __restrict__ twB, unsigned short* __restrict__ twBlo)
{
    int gid = blockIdx.x * 256 + threadIdx.x;
    if (gid < 2048) hist[gid] = 0;
    if (blockIdx.x < 48) {
        int idx = gid;                    // 0..12287
        int kk = idx >> 12, o = (idx >> 6) & 63, i = idx & 63;
        wAb[idx] = f2bf(cw[o * 192 + i * 3 + kk]);
    } else if (blockIdx.x < 96) {
        int idx = gid - 48 * 256;         // 0..12287
        int mm = idx >> 12, rem = idx & 4095;
        int g = rem >> 6, k = rem & 63;
        twB[idx] = f2bf(tw[mm * 4096 + k * 64 + g]);
    } else {                              // blocks 96..111: W2 split-lo
        int idx = gid - 96 * 256;         // 0..4095
        int g = idx >> 6, k = idx & 63;
        float v = tw[2 * 4096 + k * 64 + g];
        unsigned short hi = f2bf(v);
        twBlo[idx] = f2bf(v - bflo((unsigned)hi));
    }
}

// ---------------- dispatch 2: convln (blocks 0..2047) U hist (2048..2175) --
__global__ __launch_bounds__(256, 4)
void k_main(const float* __restrict__ x, const unsigned short* __restrict__ wAb,
            const float* __restrict__ cb, const float* __restrict__ lg,
            const float* __restrict__ lb, float* __restrict__ h_in,
            float* __restrict__ partials,
            const int* __restrict__ ei, int* __restrict__ hist)
{
    if (blockIdx.x >= NB) {               // ---- hist part (whole blocks) ----
        int e = (blockIdx.x - NB) * 256 + threadIdx.x;
        unsigned long long bal = __ballot(ei[2 * e + 1] != 0);
        int m = (bal != 0ull) ? 1 : 0;
        atomicAdd(&hist[edge_dst(ei, m, e)], 1);
        return;
    }
    __shared__ __align__(16) unsigned short xT[36 * 72];
    __shared__ float hT[32 * 65];
    __shared__ float red1[64], red2[64];
    __shared__ float wsum[8];
    __shared__ float bcast[2];

    const int b = blockIdx.x, j = threadIdx.x;
    const float* __restrict__ xg = x + (size_t)b * NTC;

    {   // stage x -> bf16 xT[t+2][i]; zero-pad rows 0,1,34,35
        unsigned* xTd = (unsigned*)xT;
        int t = j & 31, p = j >> 5;
#pragma unroll
        for (int r = 0; r < 4; ++r) {
            int i0 = (r * 8 + p) * 2;
            float v0 = xg[i0 * 32 + t];
            float v1 = xg[(i0 + 1) * 32 + t];
            xTd[(t + 2) * 36 + (i0 >> 1)] = pk2(v0, v1);
        }
        if (j < 72)       xTd[j] = 0u;
        else if (j < 144) xTd[1224 + (j - 72)] = 0u;   // rows 34,35
    }
    __syncthreads();

    const int lane = j & 63, w = j >> 6;
    const int n16 = lane & 15, quad = lane >> 4;

    bf16x8 afr[3][2];
#pragma unroll
    for (int kk = 0; kk < 3; ++kk)
#pragma unroll
        for (int s = 0; s < 2; ++s) {
            int off16 = (kk * 64 + w * 16 + n16) * 64 + s * 32 + quad * 8;
            afr[kk][s] = *(const bf16x8*)(wAb + off16);
        }

    f32x4 acc0 = {0.f, 0.f, 0.f, 0.f};
    f32x4 acc1 = {0.f, 0.f, 0.f, 0.f};
#pragma unroll
    for (int kk = 0; kk < 3; ++kk)
#pragma unroll
        for (int s = 0; s < 2; ++s) {
            bf16x8 b0 = *(const bf16x8*)(xT + (n16 + kk) * 72 + s * 32 + quad * 8);
            bf16x8 b1 = *(const bf16x8*)(xT + (16 + n16 + kk) * 72 + s * 32 + quad * 8);
            acc0 = __builtin_amdgcn_mfma_f32_16x16x32_bf16(afr[kk][s], b0, acc0, 0, 0, 0);
            acc1 = __builtin_amdgcn_mfma_f32_16x16x32_bf16(afr[kk][s], b1, acc1, 0, 0, 0);
        }

    float vals[2][4];
    float s1 = 0.f, s2 = 0.f;
#pragma unroll
    for (int r = 0; r < 4; ++r) {
        float cbv = cb[w * 16 + quad * 4 + r];
        float v0 = acc0[r] + cbv;
        float v1 = acc1[r] + cbv;
        v0 = (v0 >= 0.f) ? v0 : SLOPE_F * v0;
        v1 = (v1 >= 0.f) ? v1 : SLOPE_F * v1;
        vals[0][r] = v0; vals[1][r] = v1;
        s1 += v0 + v1; s2 += v0 * v0 + v1 * v1;
    }
#pragma unroll
    for (int off = 32; off > 0; off >>= 1) {
        s1 += __shfl_down(s1, off, 64);
        s2 += __shfl_down(s2, off, 64);
    }
    if (lane == 0) { wsum[w] = s1; wsum[4 + w] = s2; }
    __syncthreads();
    if (j == 0) {
        float S1 = wsum[0] + wsum[1] + wsum[2] + wsum[3];
        float S2 = wsum[4] + wsum[5] + wsum[6] + wsum[7];
        float mu  = S1 * (1.f / 2048.f);
        float var = S2 * (1.f / 2048.f) - mu * mu;
        bcast[0] = mu;
        bcast[1] = rsqrtf(var + EPS_F);
    }
    __syncthreads();
    const float mu = bcast[0], rs = bcast[1];
    float po1[4] = {0.f, 0.f, 0.f, 0.f}, po2[4] = {0.f, 0.f, 0.f, 0.f};
#pragma unroll
    for (int nt = 0; nt < 2; ++nt) {
        int t = nt * 16 + n16;
#pragma unroll
        for (int r = 0; r < 4; ++r) {
            int o = w * 16 + quad * 4 + r;
            float h = (vals[nt][r] - mu) * rs * lg[o * 32 + t] + lb[o * 32 + t];
            hT[t * 65 + o] = h;
            po1[r] += h; po2[r] += h * h;
        }
    }
#pragma unroll
    for (int off = 8; off > 0; off >>= 1) {
#pragma unroll
        for (int r = 0; r < 4; ++r) {
            po1[r] += __shfl_down(po1[r], off, 16);
            po2[r] += __shfl_down(po2[r], off, 16);
        }
    }
    if (n16 == 0) {
#pragma unroll
        for (int r = 0; r < 4; ++r) {
            int o = w * 16 + quad * 4 + r;
            red1[o] = po1[r];
            red2[o] = po2[r];
        }
    }
    __syncthreads();
    float* hb = h_in + (size_t)b * NTC;
#pragma unroll
    for (int r = 0; r < 8; ++r) {                  // coalesced h_in store
        int idx = j + r * 256;
        hb[idx] = hT[(idx >> 6) * 65 + (idx & 63)];
    }
    float* pb_ = partials + (size_t)b * 128;       // coalesced 512B store
    if (j < 64)       pb_[j] = red1[j];
    else if (j < 128) pb_[j] = red2[j - 64];
}

// ---------------- dispatch 3: scan (block 0) U bnred (blocks 1..64) --------
__global__ __launch_bounds__(256)
void k_mid(const int* __restrict__ hist, int* __restrict__ rowp,
           int* __restrict__ cur, const float* __restrict__ partials,
           const float* __restrict__ bg, const float* __restrict__ bb,
           float* __restrict__ stats)
{
    __shared__ int part[256];
    __shared__ float r1[4], r2[4];
    const int j = threadIdx.x;
    if (blockIdx.x == 0) {                // ---- CSR row-pointer scan ----
        int loc[8]; int s = 0;
#pragma unroll
        for (int r = 0; r < 8; ++r) { loc[r] = hist[j * 8 + r]; s += loc[r]; }
        part[j] = s;
        __syncthreads();
        for (int off = 1; off < 256; off <<= 1) {
            int v = (j >= off) ? part[j - off] : 0;
            __syncthreads();
            part[j] += v;
            __syncthreads();
        }
        int excl = part[j] - s;
#pragma unroll
        for (int r = 0; r < 8; ++r) {
            rowp[j * 8 + r] = excl;
            cur [j * 8 + r] = excl;
            excl += loc[r];
        }
        if (j == 255) rowp[2048] = excl;  // == NE
        return;
    }
    // ---- BN partial reduce, c = blockIdx.x - 1 ----
    const int c = blockIdx.x - 1;
    float s1 = 0.f, s2 = 0.f;
    for (int b = j; b < NB; b += 256) {
        const float* p = partials + (size_t)b * 128;
        s1 += p[c];
        s2 += p[64 + c];
    }
#pragma unroll
    for (int off = 32; off > 0; off >>= 1) {
        s1 += __shfl_down(s1, off, 64);
        s2 += __shfl_down(s2, off, 64);
    }
    if ((j & 63) == 0) { r1[j >> 6] = s1; r2[j >> 6] = s2; }
    __syncthreads();
    if (j == 0) {
        float S1 = r1[0] + r1[1] + r1[2] + r1[3];
        float S2 = r2[0] + r2[1] + r2[2] + r2[3];
        const float inv_n = 1.f / 65536.f;
        float mu  = S1 * inv_n;
        float var = S2 * inv_n - mu * mu;
        float rs  = rsqrtf(var + EPS_F);
        float sc  = bg[c] * rs;
        stats[128 + c] = sc;
        stats[192 + c] = bb[c] - mu * sc;
    }
}

// ---------------- dispatch 4: zlite (blocks 0..2047) U scat (2048..2175) ---
__global__ __launch_bounds__(256)
void k_zs(const float* __restrict__ h_in, const float* __restrict__ stats,
          unsigned short* __restrict__ zb16,
          const int* __restrict__ ei, const float* __restrict__ ew,
          int* __restrict__ cur, int* __restrict__ csrs, float* __restrict__ csrw)
{
    const int j = threadIdx.x;
    if (blockIdx.x >= NB) {               // ---- CSR scatter ----
        int e = (blockIdx.x - NB) * 256 + j;
        unsigned long long bal = __ballot(ei[2 * e + 1] != 0);
        int m = (bal != 0ull) ? 1 : 0;
        int d = edge_dst(ei, m, e);
        int pos = atomicAdd(&cur[d], 1);
        csrs[pos] = edge_src(ei, m, e);
        csrw[pos] = ew[e];
        return;
    }
    // ---- z = leaky(BN(h)) -> bf16 stream ----
    __shared__ float scs[64], shs[64];
    const int b = blockIdx.x;
    if (j < 64)        scs[j] = stats[128 + j];
    else if (j < 128)  shs[j - 64] = stats[192 + (j - 64)];
    __syncthreads();
    const float4* hb = (const float4*)(h_in + (size_t)b * NTC);
    float4 a = hb[2 * j], c4 = hb[2 * j + 1];     // elems 8j..8j+7 (t*64+c order)
    const int c0 = (j * 8) & 63;
    float z0 = a.x  * scs[c0+0] + shs[c0+0];
    float z1 = a.y  * scs[c0+1] + shs[c0+1];
    float z2 = a.z  * scs[c0+2] + shs[c0+2];
    float z3 = a.w  * scs[c0+3] + shs[c0+3];
    float z4 = c4.x * scs[c0+4] + shs[c0+4];
    float z5 = c4.y * scs[c0+5] + shs[c0+5];
    float z6 = c4.z * scs[c0+6] + shs[c0+6];
    float z7 = c4.w * scs[c0+7] + shs[c0+7];
    z0 = (z0 >= 0.f) ? z0 : SLOPE_F * z0;  z1 = (z1 >= 0.f) ? z1 : SLOPE_F * z1;
    z2 = (z2 >= 0.f) ? z2 : SLOPE_F * z2;  z3 = (z3 >= 0.f) ? z3 : SLOPE_F * z3;
    z4 = (z4 >= 0.f) ? z4 : SLOPE_F * z4;  z5 = (z5 >= 0.f) ? z5 : SLOPE_F * z5;
    z6 = (z6 >= 0.f) ? z6 : SLOPE_F * z6;  z7 = (z7 >= 0.f) ? z7 : SLOPE_F * z7;
    uint4 q;
    q.x = pk2(z0, z1); q.y = pk2(z2, z3); q.z = pk2(z4, z5); q.w = pk2(z6, z7);
    ((uint4*)(zb16 + (size_t)b * NTC))[j] = q;
}

// ---------------- hop 1: PURE gather z (bf16) -> p1 int16 ------------------
// All epilogue math (h + z@W0 + p1@W1 + tb) moved to k_hop2 -- p1 there is
// dequant(p1q), the same value this kernel would feed its W1-MFMA (and
// better than the old bf16 A-input). Kills the out write here and the out
// RMW in hop2: 100.5 MB of out HBM traffic -> 33.5 MB.
__global__ __launch_bounds__(256, 6)
void k_hop1(const unsigned short* __restrict__ p_in, const int* __restrict__ rowp,
            const int* __restrict__ csrs, const float* __restrict__ csrw,
            unsigned short* __restrict__ p1q, float* __restrict__ p1scl)
{
    __shared__ float mred[4];
    const int d = blockIdx.x, j = threadIdx.x;
    const int beg = rowp[d], end = rowp[d + 1];
    float acc[8];
#pragma unroll
    for (int r = 0; r < 8; ++r) acc[r] = 0.f;
    int e = beg;
    for (; e + 8 <= end; e += 8) {                // 8 gathers in flight
        int   s0 = csrs[e],   s1 = csrs[e+1], s2 = csrs[e+2], s3 = csrs[e+3];
        int   s4 = csrs[e+4], s5 = csrs[e+5], s6 = csrs[e+6], s7 = csrs[e+7];
        float w0 = csrw[e],   w1 = csrw[e+1], w2 = csrw[e+2], w3 = csrw[e+3];
        float w4 = csrw[e+4], w5 = csrw[e+5], w6 = csrw[e+6], w7 = csrw[e+7];
        uint4 v0 = ((const uint4*)(p_in + (size_t)s0 * NTC))[j];
        uint4 v1 = ((const uint4*)(p_in + (size_t)s1 * NTC))[j];
        uint4 v2 = ((const uint4*)(p_in + (size_t)s2 * NTC))[j];
        uint4 v3 = ((const uint4*)(p_in + (size_t)s3 * NTC))[j];
        uint4 v4 = ((const uint4*)(p_in + (size_t)s4 * NTC))[j];
        uint4 v5 = ((const uint4*)(p_in + (size_t)s5 * NTC))[j];
        uint4 v6 = ((const uint4*)(p_in + (size_t)s6 * NTC))[j];
        uint4 v7 = ((const uint4*)(p_in + (size_t)s7 * NTC))[j];
        accv8(acc, v0, w0); accv8(acc, v1, w1);
        accv8(acc, v2, w2); accv8(acc, v3, w3);
        accv8(acc, v4, w4); accv8(acc, v5, w5);
        accv8(acc, v6, w6); accv8(acc, v7, w7);
    }
    for (; e + 2 <= end; e += 2) {
        int s0 = csrs[e],  s1 = csrs[e+1];
        float w0 = csrw[e], w1 = csrw[e+1];
        uint4 v0 = ((const uint4*)(p_in + (size_t)s0 * NTC))[j];
        uint4 v1 = ((const uint4*)(p_in + (size_t)s1 * NTC))[j];
        accv8(acc, v0, w0); accv8(acc, v1, w1);
    }
    if (e < end) {
        int s0 = csrs[e];
        float w0 = csrw[e];
        uint4 v0 = ((const uint4*)(p_in + (size_t)s0 * NTC))[j];
        accv8(acc, v0, w0);
    }

    // ---- per-node max|p1| reduce (for int16 scale) ----
    const int lane = j & 63, w = j >> 6;
    float m = 0.f;
#pragma unroll
    for (int r = 0; r < 8; ++r) m = fmaxf(m, fabsf(acc[r]));
#pragma unroll
    for (int off = 32; off > 0; off >>= 1)
        m = fmaxf(m, __shfl_down(m, off, 64));
    if (lane == 0) mred[w] = m;
    __syncthreads();
    const float mv = fmaxf(fmaxf(mred[0], mred[1]), fmaxf(mred[2], mred[3]));
    const float inv = (mv > 0.f) ? (32767.f / mv) : 0.f;
    if (j == 0) p1scl[d] = mv * (1.f / 32767.f);

    // int16 p1 store: thread j owns elems 8j..8j+7 of [t][c] row-major
    uint4 qv;
    qv.x = pkq2(acc[0], acc[1], inv);
    qv.y = pkq2(acc[2], acc[3], inv);
    qv.z = pkq2(acc[4], acc[5], inv);
    qv.w = pkq2(acc[6], acc[7], inv);
    ((uint4*)(p1q + (size_t)d * NTC))[j] = qv;
}

// ---------------- hop 2: int16 gather + FULL fused epilogue ----------------
// out = h + tb + z@W0 + p1@W1 + (p2H@W2H + p2H@W2L + p2L@W2H)  -- pure store.
__global__ __launch_bounds__(256, 4)
void k_hop2(const unsigned short* __restrict__ p1q, const float* __restrict__ p1scl,
            const unsigned short* __restrict__ zb16, const float* __restrict__ h_in,
            const int* __restrict__ rowp, const int* __restrict__ csrs,
            const float* __restrict__ csrw,
            const unsigned short* __restrict__ twB,    // W0 @0, W1 @4096, W2hi @8192
            const unsigned short* __restrict__ twB2lo, // W2 lo, B-layout
            const float* __restrict__ tb,
            float* __restrict__ out)
{
    __shared__ __align__(16) unsigned short zA[32 * 64];   // bf16 z[d]
    __shared__ __align__(16) unsigned short pA[32 * 64];   // bf16 p1[d] (dequant)
    __shared__ __align__(16) unsigned short pH[32 * 64];   // bf16 p2 hi
    __shared__ __align__(16) unsigned short pL[32 * 64];   // bf16 p2 lo
    __shared__ float hl[32 * 65];                          // fp32 h residual
    const int d = blockIdx.x, j = threadIdx.x;

    {   // stage own rows: z (bf16 copy), h (fp32), p1 (dequant int16 -> bf16)
        uint4 zv = ((const uint4*)(zb16 + (size_t)d * NTC))[j];
        ((uint4*)zA)[j] = zv;
        const float4* hb4 = (const float4*)(h_in + (size_t)d * NTC);
        float4 h0 = hb4[2 * j], h1 = hb4[2 * j + 1];
        int tt = j >> 3, c0 = (j & 7) * 8;
        float* q = &hl[tt * 65 + c0];
        q[0] = h0.x; q[1] = h0.y; q[2] = h0.z; q[3] = h0.w;
        q[4] = h1.x; q[5] = h1.y; q[6] = h1.z; q[7] = h1.w;
        uint4 pq = ((const uint4*)(p1q + (size_t)d * NTC))[j];
        const float scl = p1scl[d];
        uint4 pb;
        pb.x = pk2(scl * (float)(short)(pq.x & 0xFFFFu), scl * (float)(short)(pq.x >> 16));
        pb.y = pk2(scl * (float)(short)(pq.y & 0xFFFFu), scl * (float)(short)(pq.y >> 16));
        pb.z = pk2(scl * (float)(short)(pq.z & 0xFFFFu), scl * (float)(short)(pq.z >> 16));
        pb.w = pk2(scl * (float)(short)(pq.w & 0xFFFFu), scl * (float)(short)(pq.w >> 16));
        ((uint4*)pA)[j] = pb;
    }

    const int beg = rowp[d], end = rowp[d + 1];
    float acc[8];
#pragma unroll
    for (int r = 0; r < 8; ++r) acc[r] = 0.f;
    int e = beg;
    for (; e + 8 <= end; e += 8) {                // 8 gathers in flight (16B each)
        int   s0 = csrs[e],   s1 = csrs[e+1], s2 = csrs[e+2], s3 = csrs[e+3];
        int   s4 = csrs[e+4], s5 = csrs[e+5], s6 = csrs[e+6], s7 = csrs[e+7];
        float w0 = csrw[e]   * p1scl[s0];
        float w1 = csrw[e+1] * p1scl[s1];
        float w2 = csrw[e+2] * p1scl[s2];
        float w3 = csrw[e+3] * p1scl[s3];
        float w4 = csrw[e+4] * p1scl[s4];
        float w5 = csrw[e+5] * p1scl[s5];
        float w6 = csrw[e+6] * p1scl[s6];
        float w7 = csrw[e+7] * p1scl[s7];
        uint4 v0 = ((const uint4*)(p1q + (size_t)s0 * NTC))[j];
        uint4 v1 = ((const uint4*)(p1q + (size_t)s1 * NTC))[j];
        uint4 v2 = ((const uint4*)(p1q + (size_t)s2 * NTC))[j];
        uint4 v3 = ((const uint4*)(p1q + (size_t)s3 * NTC))[j];
        uint4 v4 = ((const uint4*)(p1q + (size_t)s4 * NTC))[j];
        uint4 v5 = ((const uint4*)(p1q + (size_t)s5 * NTC))[j];
        uint4 v6 = ((const uint4*)(p1q + (size_t)s6 * NTC))[j];
        uint4 v7 = ((const uint4*)(p1q + (size_t)s7 * NTC))[j];
        acci16(acc, v0, w0); acci16(acc, v1, w1);
        acci16(acc, v2, w2); acci16(acc, v3, w3);
        acci16(acc, v4, w4); acci16(acc, v5, w5);
        acci16(acc, v6, w6); acci16(acc, v7, w7);
    }
    for (; e + 2 <= end; e += 2) {
        int s0 = csrs[e],  s1 = csrs[e+1];
        float w0 = csrw[e]   * p1scl[s0];
        float w1 = csrw[e+1] * p1scl[s1];
        uint4 v0 = ((const uint4*)(p1q + (size_t)s0 * NTC))[j];
        uint4 v1 = ((const uint4*)(p1q + (size_t)s1 * NTC))[j];
        acci16(acc, v0, w0); acci16(acc, v1, w1);
    }
    if (e < end) {
        int s0 = csrs[e];
        float w0 = csrw[e] * p1scl[s0];
        uint4 v0 = ((const uint4*)(p1q + (size_t)s0 * NTC))[j];
        acci16(acc, v0, w0);
    }
    {   // hi/lo split-pack p2 into LDS (thread j owns elems 8j..8j+7, [t][c])
        uint4 qh, ql;
        spl2(acc[0], acc[1], qh.x, ql.x);
        spl2(acc[2], acc[3], qh.y, ql.y);
        spl2(acc[4], acc[5], qh.z, ql.z);
        spl2(acc[6], acc[7], qh.w, ql.w);
        ((uint4*)pH)[j] = qh;
        ((uint4*)pL)[j] = ql;
    }
    __syncthreads();

    const int lane = j & 63, w = j >> 6;
    const int n16 = lane & 15, quad = lane >> 4;
    const int g = w * 16 + n16;

    f32x4 d0 = {0.f, 0.f, 0.f, 0.f};
    f32x4 d1 = {0.f, 0.f, 0.f, 0.f};
    {   // z @ W0
        bf16x8 a00 = *(const bf16x8*)(zA + (n16)      * 64 +      quad * 8);
        bf16x8 a01 = *(const bf16x8*)(zA + (n16)      * 64 + 32 + quad * 8);
        bf16x8 a10 = *(const bf16x8*)(zA + (16 + n16) * 64 +      quad * 8);
        bf16x8 a11 = *(const bf16x8*)(zA + (16 + n16) * 64 + 32 + quad * 8);
        bf16x8 b0  = *(const bf16x8*)(twB + g * 64 +      quad * 8);
        bf16x8 b1  = *(const bf16x8*)(twB + g * 64 + 32 + quad * 8);
        d0 = __builtin_amdgcn_mfma_f32_16x16x32_bf16(a00, b0, d0, 0, 0, 0);
        d0 = __builtin_amdgcn_mfma_f32_16x16x32_bf16(a01, b1, d0, 0, 0, 0);
        d1 = __builtin_amdgcn_mfma_f32_16x16x32_bf16(a10, b0, d1, 0, 0, 0);
        d1 = __builtin_amdgcn_mfma_f32_16x16x32_bf16(a11, b1, d1, 0, 0, 0);
    }
    {   // p1 @ W1
        bf16x8 a00 = *(const bf16x8*)(pA + (n16)      * 64 +      quad * 8);
        bf16x8 a01 = *(const bf16x8*)(pA + (n16)      * 64 + 32 + quad * 8);
        bf16x8 a10 = *(const bf16x8*)(pA + (16 + n16) * 64 +      quad * 8);
        bf16x8 a11 = *(const bf16x8*)(pA + (16 + n16) * 64 + 32 + quad * 8);
        bf16x8 b0  = *(const bf16x8*)(twB + 4096 + g * 64 +      quad * 8);
        bf16x8 b1  = *(const bf16x8*)(twB + 4096 + g * 64 + 32 + quad * 8);
        d0 = __builtin_amdgcn_mfma_f32_16x16x32_bf16(a00, b0, d0, 0, 0, 0);
        d0 = __builtin_amdgcn_mfma_f32_16x16x32_bf16(a01, b1, d0, 0, 0, 0);
        d1 = __builtin_amdgcn_mfma_f32_16x16x32_bf16(a10, b0, d1, 0, 0, 0);
        d1 = __builtin_amdgcn_mfma_f32_16x16x32_bf16(a11, b1, d1, 0, 0, 0);
    }
    {   // p2 split @ W2: hi@hi + hi@lo + lo@hi
        bf16x8 ah00 = *(const bf16x8*)(pH + (n16)      * 64 +      quad * 8);
        bf16x8 ah01 = *(const bf16x8*)(pH + (n16)      * 64 + 32 + quad * 8);
        bf16x8 ah10 = *(const bf16x8*)(pH + (16 + n16) * 64 +      quad * 8);
        bf16x8 ah11 = *(const bf16x8*)(pH + (16 + n16) * 64 + 32 + quad * 8);
        bf16x8 b0h  = *(const bf16x8*)(twB + 8192 + g * 64 +      quad * 8);
        bf16x8 b1h  = *(const bf16x8*)(twB + 8192 + g * 64 + 32 + quad * 8);
        d0 = __builtin_amdgcn_mfma_f32_16x16x32_bf16(ah00, b0h, d0, 0, 0, 0);
        d0 = __builtin_amdgcn_mfma_f32_16x16x32_bf16(ah01, b1h, d0, 0, 0, 0);
        d1 = __builtin_amdgcn_mfma_f32_16x16x32_bf16(ah10, b0h, d1, 0, 0, 0);
        d1 = __builtin_amdgcn_mfma_f32_16x16x32_bf16(ah11, b1h, d1, 0, 0, 0);
        bf16x8 b0l  = *(const bf16x8*)(twB2lo + g * 64 +      quad * 8);
        bf16x8 b1l  = *(const bf16x8*)(twB2lo + g * 64 + 32 + quad * 8);
        d0 = __builtin_amdgcn_mfma_f32_16x16x32_bf16(ah00, b0l, d0, 0, 0, 0);
        d0 = __builtin_amdgcn_mfma_f32_16x16x32_bf16(ah01, b1l, d0, 0, 0, 0);
        d1 = __builtin_amdgcn_mfma_f32_16x16x32_bf16(ah10, b0l, d1, 0, 0, 0);
        d1 = __builtin_amdgcn_mfma_f32_16x16x32_bf16(ah11, b1l, d1, 0, 0, 0);
        bf16x8 al00 = *(const bf16x8*)(pL + (n16)      * 64 +      quad * 8);
        bf16x8 al01 = *(const bf16x8*)(pL + (n16)      * 64 + 32 + quad * 8);
        bf16x8 al10 = *(const bf16x8*)(pL + (16 + n16) * 64 +      quad * 8);
        bf16x8 al11 = *(const bf16x8*)(pL + (16 + n16) * 64 + 32 + quad * 8);
        d0 = __builtin_amdgcn_mfma_f32_16x16x32_bf16(al00, b0h, d0, 0, 0, 0);
        d0 = __builtin_amdgcn_mfma_f32_16x16x32_bf16(al01, b1h, d0, 0, 0, 0);
        d1 = __builtin_amdgcn_mfma_f32_16x16x32_bf16(al10, b0h, d1, 0, 0, 0);
        d1 = __builtin_amdgcn_mfma_f32_16x16x32_bf16(al11, b1h, d1, 0, 0, 0);
    }

    const float tbg = tb[g];
    float* ob = out + (size_t)d * NTC + g * 32;   // out[b][g][t], pure store
    {
        float4 v;                                  // mtile 0: t = quad*4..+3
        v.x = d0[0] + tbg + hl[(quad * 4 + 0) * 65 + g];
        v.y = d0[1] + tbg + hl[(quad * 4 + 1) * 65 + g];
        v.z = d0[2] + tbg + hl[(quad * 4 + 2) * 65 + g];
        v.w = d0[3] + tbg + hl[(quad * 4 + 3) * 65 + g];
        *(float4*)(ob + quad * 4) = v;
    }
    {
        float4 v;                                  // mtile 1: t = 16+quad*4..+3
        v.x = d1[0] + tbg + hl[(16 + quad * 4 + 0) * 65 + g];
        v.y = d1[1] + tbg + hl[(16 + quad * 4 + 1) * 65 + g];
        v.z = d1[2] + tbg + hl[(16 + quad * 4 + 2) * 65 + g];
        v.w = d1[3] + tbg + hl[(16 + quad * 4 + 3) * 65 + g];
        *(float4*)(ob + 16 + quad * 4) = v;
    }
}

// ---------------- launch ----------------
// workspace floats:
//   [0, 4194304)          h_in [b][t][c] fp32
//   [4194304, 6291456)    p1q int16 [b][t][c] (ushort, 8MB)
//   [6291456, 6293504)    p1scl [b] fp32 (8KB)
//   [8388608, 10485760)   z_bf16 [b][t][c] (ushort, 8MB)
//   [10485760, +256)      stats (scale[64]@128, shift[64]@192)
//   [10486016, +6144)     wAb (bf16 conv A-layout, 24KB)
//   [10492160, +6144)     twB (bf16 tag W^T B-layout, 24KB; W0/W1/W2hi)
//   [10498304, +262144)   partials [b][128]
//   [10760448, ...)       ints: hist(2048) rowp(2049+pad) cur(2048)
//                               csrs(32768) csrw(32768)
//   [10832640, +2048)     twBlo (bf16 W2 split-lo B-layout, 8KB)
extern "C" void kernel_launch(void* const* d_in, const int* in_sizes, int n_in,
                              void* d_out, int out_size, void* d_ws, size_t ws_size,
                              hipStream_t stream)
{
    const float* x  = (const float*)d_in[0];
    const int*   ei = (const int*)  d_in[1];
    const float* ew = (const float*)d_in[2];
    const float* cw = (const float*)d_in[3];
    const float* cb = (const float*)d_in[4];
    const float* lg = (const float*)d_in[5];
    const float* lb = (const float*)d_in[6];
    const float* bg = (const float*)d_in[7];
    const float* bb = (const float*)d_in[8];
    const float* tw = (const float*)d_in[9];
    const float* tb = (const float*)d_in[10];
    float* out = (float*)d_out;
    float* ws  = (float*)d_ws;

    float*          h_in  = ws;
    unsigned short* p1q   = (unsigned short*)(ws + 4194304);
    float*          p1scl = ws + 6291456;
    unsigned short* zbf   = (unsigned short*)(ws + 8388608);
    float*          stats = ws + 10485760;
    unsigned short* wAb   = (unsigned short*)(ws + 10486016);
    unsigned short* twB   = (unsigned short*)(ws + 10492160);
    float*          parts = ws + 10498304;
    int*            ib    = (int*)(ws + 10760448);
    unsigned short* twBlo = (unsigned short*)(ws + 10832640);
    int*   hist  = ib;
    int*   rowp  = ib + 2048;
    int*   cur   = ib + 4100;
    int*   csrs  = ib + 6148;
    float* csrw  = (float*)(ib + 38916);

    k_pre  <<<112,      256, 0, stream>>>(hist, cw, wAb, tw, twB, twBlo);
    k_main <<<NB + 128, 256, 0, stream>>>(x, wAb, cb, lg, lb, h_in, parts, ei, hist);
    k_mid  <<<65,       256, 0, stream>>>(hist, rowp, cur, parts, bg, bb, stats);
    k_zs   <<<NB + 128, 256, 0, stream>>>(h_in, stats, zbf, ei, ew, cur, csrs, csrw);
    k_hop1 <<<NB,       256, 0, stream>>>(zbf, rowp, csrs, csrw, p1q, p1scl);
    k_hop2 <<<NB,       256, 0, stream>>>(p1q, p1scl, zbf, h_in, rowp, csrs, csrw,
                                          twB, twBlo, tb, out);
}